// Round 16
// baseline (604.437 us; speedup 1.0000x reference)
//
#include <hip/hip_runtime.h>

#define U_NUM   100000
#define I_NUM   50000
#define FCT     64
#define NEDGE   3200000
#define BATCH   16384
#define NROWS   (U_NUM + I_NUM)      // 150000
#define TOTSLOTS (2 * NEDGE)         // 6400000

#define BSH 6                        // 64 rows per bucket
#define NBU 1563                     // ceil(100000/64)
#define NBI 782                      // ceil(50000/64)
#define NBUCK (NBU + NBI)            // 2345
#define NCLS 4                       // scatter classes (sweep count)
#define NQ4  587                     // ceil(NBUCK/4) buckets per class
#define SUBS 256                     // slices (count blocks; scatter blocks per class)
#define BUFSZ 6912                   // LDS payload buffer (expected fill 6250, +8 sigma)

__device__ __forceinline__ unsigned short f2b(float f) {
    unsigned int x = __float_as_uint(f);
    unsigned int r = (x + 0x7FFFu + ((x >> 16) & 1u)) >> 16;   // RNE
    return (unsigned short)r;
}
__device__ __forceinline__ float b2f(unsigned short u) {
    return __uint_as_float(((unsigned int)u) << 16);
}

// ---------------- fp32 -> bf16 table conversion ----------------
__global__ void conv_kernel(const float* __restrict__ in, unsigned short* __restrict__ out, int n4) {
    int t = blockIdx.x * blockDim.x + threadIdx.x;
    if (t >= n4) return;
    float4 v = *reinterpret_cast<const float4*>(in + (size_t)t * 4);
    ushort4 o;
    o.x = f2b(v.x); o.y = f2b(v.y); o.z = f2b(v.z); o.w = f2b(v.w);
    *reinterpret_cast<ushort4*>(out + (size_t)t * 4) = o;
}

// ---------------- single-sweep per-(sub,bucket) count ----------------
__global__ void __launch_bounds__(256) count256_kernel(const int* __restrict__ eu,
                                                       const int* __restrict__ ei,
                                                       int* __restrict__ cntmat256) {
    __shared__ int lcnt[NBUCK];
    for (int k = threadIdx.x; k < NBUCK; k += 256) lcnt[k] = 0;
    __syncthreads();
    int sub = blockIdx.x;
    for (int t = sub * 256 + (int)threadIdx.x; t < NEDGE; t += SUBS * 256) {
        int u = eu[t];
        int i = ei[t];
        atomicAdd(&lcnt[u >> BSH], 1);
        atomicAdd(&lcnt[NBU + (i >> BSH)], 1);
    }
    __syncthreads();
    int* row = cntmat256 + (size_t)sub * NBUCK;
    for (int k = threadIdx.x; k < NBUCK; k += 256) row[k] = lcnt[k];
}

// ---------------- per-bucket scan over 256 subs (PARITY-GROUPED order) ----------------
// Scatter block for (cls,sub) has XCD = ((sub&1)<<2)|cls, so within a bucket we order
// runs even-subs-first then odd-subs: adjacent runs share an XCD (one seam per bucket),
// keeping partial-line writebacks suppressed. Any bijective order is CORRECT; this one
// is merely locality-optimal for the 4-class grid.
__global__ void __launch_bounds__(256) bscan2_kernel(const int* __restrict__ cntmat256,
                                                     int* __restrict__ localpfx,
                                                     int* __restrict__ btot) {
    __shared__ int ws[4];
    int b = blockIdx.x;
    int t = threadIdx.x;
    int sub = (t < 128) ? (2 * t) : (2 * (t - 128) + 1);   // scan position t -> sub
    int c = cntmat256[(size_t)sub * NBUCK + b];
    int inc = c;
#pragma unroll
    for (int o = 1; o < 64; o <<= 1) {
        int x = __shfl_up(inc, o);
        if ((t & 63) >= o) inc += x;
    }
    if ((t & 63) == 63) ws[t >> 6] = inc;
    __syncthreads();
    int carry = 0;
#pragma unroll
    for (int w = 0; w < 4; w++) {
        if ((t >> 6) > w) carry += ws[w];
    }
    localpfx[(size_t)b * 256 + sub] = carry + inc - c;   // exclusive prefix (tau-order)
    if (t == 255) btot[b] = carry + inc;                 // bucket total
}

// ---------------- single-block exclusive scan over bucket totals -> bbase ----------------
__global__ void bscan_kernel(const int* __restrict__ btot, int* __restrict__ bbase) {
    __shared__ int s[256];
    int t = threadIdx.x;
    int v[10];                          // 256*10 = 2560 >= NBUCK
    int tot = 0;
#pragma unroll
    for (int k = 0; k < 10; k++) {
        int idx = t * 10 + k;
        v[k] = (idx < NBUCK) ? btot[idx] : 0;
        tot += v[k];
    }
    s[t] = tot;
    __syncthreads();
    for (int off = 1; off < 256; off <<= 1) {
        int x = (t >= off) ? s[t - off] : 0;
        __syncthreads();
        s[t] += x;
        __syncthreads();
    }
    int p = s[t] - tot;
#pragma unroll
    for (int k = 0; k < 10; k++) {
        int idx = t * 10 + k;
        if (idx < NBUCK) bbase[idx] = p;
        p += v[k];
    }
    if (t == 255) bbase[NBUCK] = TOTSLOTS;
}

// ---------------- multisplit scatter: 4 classes, LDS-buffered rank-scatter + flush ----------------
__global__ void __launch_bounds__(256) scatterB_kernel(const int* __restrict__ eu,
                                                       const int* __restrict__ ei,
                                                       const float* __restrict__ vui,
                                                       const float* __restrict__ viu,
                                                       const int* __restrict__ cntmat256,
                                                       const int* __restrict__ localpfx,
                                                       const int* __restrict__ bbase,
                                                       int2* __restrict__ staging) {
    __shared__ int lofs[NQ4 + 1];
    __shared__ int lbase[NQ4];
    __shared__ int lrank[NQ4];
    __shared__ int2 lbuf[BUFSZ];     // 55.3 KB; total static ~62 KB
    int cls = blockIdx.x & 3;
    int sub = blockIdx.x >> 2;
    for (int k = threadIdx.x; k < NQ4; k += 256) {
        int b = k * 4 + cls;
        if (b < NBUCK) {
            lbase[k] = bbase[b] + localpfx[(size_t)b * 256 + sub];
            lofs[k + 1] = cntmat256[(size_t)sub * NBUCK + b];
        } else {
            lbase[k] = 0;
            lofs[k + 1] = 0;
        }
        lrank[k] = 0;
    }
    if (threadIdx.x == 0) lofs[0] = 0;
    __syncthreads();
    // wave 0: inclusive scan of lofs[1..NQ4] (10 chunks of 64, carried)
    if (threadIdx.x < 64) {
        int carry = 0;
        for (int c = 0; c < 10; c++) {
            int idx = c * 64 + (int)threadIdx.x + 1;
            int v = (idx <= NQ4) ? lofs[idx] : 0;
            int inc = v;
#pragma unroll
            for (int o = 1; o < 64; o <<= 1) {
                int x = __shfl_up(inc, o);
                if ((int)threadIdx.x >= o) inc += x;
            }
            if (idx <= NQ4) lofs[idx] = carry + inc;
            carry += __shfl(inc, 63);
        }
    }
    __syncthreads();
    int total = lofs[NQ4];
    for (int t = sub * 256 + (int)threadIdx.x; t < NEDGE; t += SUBS * 256) {
        int u = eu[t];
        int i = ei[t];
        int bu = u >> BSH;
        if ((bu & 3) == cls) {
            int q = bu >> 2;
            int r = atomicAdd(&lrank[q], 1);
            int2 pay = make_int2(((u & 63) << 17) | i, __float_as_int(vui[t]));
            int pos = lofs[q] + r;
            if (pos < BUFSZ) lbuf[pos] = pay;
            else staging[lbase[q] + r] = pay;
        }
        int bid = NBU + (i >> BSH);
        if ((bid & 3) == cls) {
            int q = bid >> 2;
            int r = atomicAdd(&lrank[q], 1);
            int2 pay = make_int2(((i & 63) << 17) | u, __float_as_int(viu[t]));
            int pos = lofs[q] + r;
            if (pos < BUFSZ) lbuf[pos] = pay;
            else staging[lbase[q] + r] = pay;
        }
    }
    __syncthreads();
    int fl = min(total, BUFSZ);
    for (int t = threadIdx.x; t < fl; t += 256) {
        int lo = 0, hi = NQ4;
        while (hi - lo > 1) {
            int mid = (lo + hi) >> 1;
            if (lofs[mid] <= t) lo = mid; else hi = mid;
        }
        staging[lbase[lo] + (t - lofs[lo])] = lbuf[t];
    }
}

// ---------------- phase B: row counts -> rowptr -> row-ordered PACKED csr ----------------
__global__ void __launch_bounds__(256) rsort_kernel(const int* __restrict__ bbase,
                                                    const int2* __restrict__ staging,
                                                    unsigned int* __restrict__ csr4,
                                                    int* __restrict__ rowptr) {
    __shared__ int fillr[64];
    __shared__ int rp[64];
    int b = blockIdx.x;
    int gRowBase, rows;
    if (b < NBU) {
        gRowBase = b << BSH;
        rows = min(64, U_NUM - gRowBase);
    } else {
        int rb = (b - NBU) << BSH;
        gRowBase = U_NUM + rb;
        rows = min(64, I_NUM - rb);
    }
    if (threadIdx.x < 64) fillr[threadIdx.x] = 0;
    __syncthreads();
    int beg = bbase[b], end = bbase[b + 1];
    for (int e = beg + (int)threadIdx.x; e < end; e += 256) {
        int off = staging[e].x >> 17;
        atomicAdd(&fillr[off], 1);
    }
    __syncthreads();
    if (threadIdx.x < 64) {
        int c = fillr[threadIdx.x];
        int inc = c;
#pragma unroll
        for (int o = 1; o < 64; o <<= 1) {
            int x = __shfl_up(inc, o);
            if ((int)threadIdx.x >= o) inc += x;
        }
        int excl = beg + inc - c;
        rp[threadIdx.x] = excl;
        if ((int)threadIdx.x < rows) rowptr[gRowBase + threadIdx.x] = excl;
        fillr[threadIdx.x] = 0;
    }
    if (b == 0 && threadIdx.x == 64) rowptr[NROWS] = TOTSLOTS;
    __syncthreads();
    for (int e = beg + (int)threadIdx.x; e < end; e += 256) {
        int2 pk = staging[e];
        int off = pk.x >> 17;
        int dst = rp[off] + atomicAdd(&fillr[off], 1);
        unsigned int src = (unsigned int)(pk.x & 0x1FFFF);
        unsigned int bv = f2b(__int_as_float(pk.y)) & 0x7FFFu;
        csr4[dst] = (src << 15) | bv;
    }
}

// ---------------- propagation: half-wave per edge, ushort2 (uint) packed lanes ----------------
__global__ void __launch_bounds__(256) agg_kernel(
        const unsigned short* __restrict__ uprev, const unsigned short* __restrict__ iprev,
        unsigned short* __restrict__ unext, unsigned short* __restrict__ inext,
        const float* __restrict__ di, const float* __restrict__ dj,
        const int* __restrict__ rowptr, const unsigned int* __restrict__ csr4) {
    int wid = (blockIdx.x * 256 + threadIdx.x) >> 6;
    int lane = threadIdx.x & 63;
    if (wid >= NROWS) return;
    int half = lane >> 5;
    unsigned int dp = (unsigned int)(lane & 31);   // dim-pair index
    const unsigned int* selfU;
    const unsigned int* srcU;
    unsigned int* dstU;
    float dscale;
    unsigned int r32;
    if (wid < U_NUM) {
        r32 = (unsigned int)wid;
        selfU = (const unsigned int*)uprev;
        srcU  = (const unsigned int*)iprev;
        dstU  = (unsigned int*)unext;
        dscale = di[wid];
    } else {
        r32 = (unsigned int)(wid - U_NUM);
        selfU = (const unsigned int*)iprev;
        srcU  = (const unsigned int*)uprev;
        dstU  = (unsigned int*)inext;
        dscale = dj[wid - U_NUM];
    }
    int beg = rowptr[wid], end = rowptr[wid + 1];
    unsigned int selfIdx = (r32 << 5) | dp;
    float accx, accy;
    {
        unsigned int s = selfU[selfIdx];
        float sx = b2f((unsigned short)(s & 0xFFFFu));
        float sy = b2f((unsigned short)(s >> 16));
        accx = (half == 0) ? sx * dscale : 0.0f;
        accy = (half == 0) ? sy * dscale : 0.0f;
    }
    int e = beg;
    for (; e + 8 <= end; e += 8) {
        unsigned int pk[4], g[4];
#pragma unroll
        for (int k = 0; k < 4; k++) pk[k] = csr4[e + 2 * k + half];
#pragma unroll
        for (int k = 0; k < 4; k++) g[k] = srcU[((pk[k] >> 15) << 5) | dp];
#pragma unroll
        for (int k = 0; k < 4; k++) {
            float w = b2f((unsigned short)(pk[k] & 0x7FFFu));
            accx = fmaf(w, b2f((unsigned short)(g[k] & 0xFFFFu)), accx);
            accy = fmaf(w, b2f((unsigned short)(g[k] >> 16)), accy);
        }
    }
    for (; e < end; e += 2) {
        int idx = e + half;
        if (idx < end) {
            unsigned int pk = csr4[idx];
            unsigned int g = srcU[((pk >> 15) << 5) | dp];
            float w = b2f((unsigned short)(pk & 0x7FFFu));
            accx = fmaf(w, b2f((unsigned short)(g & 0xFFFFu)), accx);
            accy = fmaf(w, b2f((unsigned short)(g >> 16)), accy);
        }
    }
    accx += __shfl_xor(accx, 32);
    accy += __shfl_xor(accy, 32);
    if (half == 0) {
        unsigned int o = ((unsigned int)f2b(accy) << 16) | (unsigned int)f2b(accx);
        dstU[selfIdx] = o;
    }
}

// ---------------- BPR head ----------------
__global__ void __launch_bounds__(256) batch_kernel(
        const float* __restrict__ u0f, const float* __restrict__ i0f,
        const unsigned short* __restrict__ u1, const unsigned short* __restrict__ u2,
        const unsigned short* __restrict__ u3,
        const unsigned short* __restrict__ i1, const unsigned short* __restrict__ i2,
        const unsigned short* __restrict__ i3,
        const int* __restrict__ user, const int* __restrict__ ita, const int* __restrict__ itb,
        float* __restrict__ out, float* __restrict__ ls, float* __restrict__ l2a) {
    int wid = (blockIdx.x * 256 + threadIdx.x) >> 6;
    int lane = threadIdx.x & 63;
    if (wid >= BATCH) return;
    size_t uo = (size_t)user[wid] * FCT + lane;
    size_t ao = (size_t)ita[wid] * FCT + lane;
    size_t bo = (size_t)itb[wid] * FCT + lane;

    float pi, pj, l2;
    {
        float ue = u0f[uo], ie = i0f[ao], je = i0f[bo];
        pi = ue * ie; pj = ue * je; l2 = ue * ue + ie * ie + je * je;
    }
    const unsigned short* Ut[3] = {u1, u2, u3};
    const unsigned short* It[3] = {i1, i2, i3};
#pragma unroll
    for (int l = 0; l < 3; l++) {
        float ue = b2f(Ut[l][uo]), ie = b2f(It[l][ao]), je = b2f(It[l][bo]);
        pi += ue * ie;
        pj += ue * je;
        l2 += ue * ue + ie * ie + je * je;
    }
#pragma unroll
    for (int off = 32; off; off >>= 1) {
        pi += __shfl_xor(pi, off);
        pj += __shfl_xor(pj, off);
        l2 += __shfl_xor(l2, off);
    }
    if (lane == 0) {
        out[wid] = pi;
        out[BATCH + wid] = pj;
        float x = pi - pj;
        ls[wid] = fminf(x, 0.0f) - log1pf(expf(-fabsf(x)));
        l2a[wid] = 0.01f * l2;
    }
}

__global__ void final_kernel(const float* __restrict__ ls, const float* __restrict__ l2a,
                             float* __restrict__ out) {
    __shared__ float s1[256], s2[256];
    int t = threadIdx.x;
    float a = 0.f, b = 0.f;
    for (int i = t; i < BATCH; i += 256) {
        a += ls[i];
        b += l2a[i];
    }
    s1[t] = a;
    s2[t] = b;
    __syncthreads();
    for (int off = 128; off; off >>= 1) {
        if (t < off) {
            s1[t] += s1[t + off];
            s2[t] += s2[t + off];
        }
        __syncthreads();
    }
    if (t == 0) {
        float loss2 = -s1[0] / (float)BATCH;
        float l2m = s2[0] / (float)BATCH;
        out[2 * BATCH] = loss2 + l2m;
        out[2 * BATCH + 1] = loss2;
    }
}

// ---------------- launch ----------------
extern "C" void kernel_launch(void* const* d_in, const int* in_sizes, int n_in,
                              void* d_out, int out_size, void* d_ws, size_t ws_size,
                              hipStream_t stream) {
    const float* u0f = (const float*)d_in[0];
    const float* i0f = (const float*)d_in[1];
    const float* di  = (const float*)d_in[2];
    const float* dj  = (const float*)d_in[3];
    const float* vui = (const float*)d_in[4];
    const float* viu = (const float*)d_in[5];
    const int*   eu  = (const int*)d_in[6];
    const int*   ei  = (const int*)d_in[7];
    const int*   usr = (const int*)d_in[8];
    const int*   ita = (const int*)d_in[9];
    const int*   itb = (const int*)d_in[10];
    float* out = (float*)d_out;

    char* p = (char*)d_ws;
    auto alloc = [&](size_t bytes) -> char* {
        char* r = p;
        p += (bytes + 255) & ~(size_t)255;
        return r;
    };
    unsigned short* u0b = (unsigned short*)alloc((size_t)U_NUM * FCT * 2);
    unsigned short* u1b = (unsigned short*)alloc((size_t)U_NUM * FCT * 2);
    unsigned short* i0b = (unsigned short*)alloc((size_t)I_NUM * FCT * 2);
    unsigned short* i1b = (unsigned short*)alloc((size_t)I_NUM * FCT * 2);
    unsigned int* csr4 = (unsigned int*)alloc((size_t)TOTSLOTS * 4);   // 25.6 MB
    int2* staging = (int2*)alloc((size_t)TOTSLOTS * 8);                // 51.2 MB
    int* rowptr    = (int*)alloc((size_t)(NROWS + 1) * 4);
    int* cntmat256 = (int*)alloc((size_t)SUBS * NBUCK * 4);            // 2.4 MB
    int* localpfx  = (int*)alloc((size_t)NBUCK * SUBS * 4);            // 2.4 MB
    int* btot      = (int*)alloc((size_t)NBUCK * 4);
    int* bbase     = (int*)alloc((size_t)(NBUCK + 1) * 4);
    float* ls      = (float*)alloc((size_t)BATCH * 4);
    float* l2a     = (float*)alloc((size_t)BATCH * 4);
    // overlay levels 2,3 on staging (dead after rsort; written by later agg launches)
    unsigned short* u2b = (unsigned short*)staging;
    unsigned short* u3b = u2b + (size_t)U_NUM * FCT;
    unsigned short* i2b = u3b + (size_t)U_NUM * FCT;
    unsigned short* i3b = i2b + (size_t)I_NUM * FCT;

    conv_kernel<<<(U_NUM * FCT / 4 + 255) / 256, 256, 0, stream>>>(u0f, u0b, U_NUM * FCT / 4);
    conv_kernel<<<(I_NUM * FCT / 4 + 255) / 256, 256, 0, stream>>>(i0f, i0b, I_NUM * FCT / 4);

    count256_kernel<<<SUBS, 256, 0, stream>>>(eu, ei, cntmat256);
    bscan2_kernel<<<NBUCK, 256, 0, stream>>>(cntmat256, localpfx, btot);
    bscan_kernel<<<1, 256, 0, stream>>>(btot, bbase);

    scatterB_kernel<<<SUBS * NCLS, 256, 0, stream>>>(eu, ei, vui, viu, cntmat256, localpfx, bbase, staging);
    rsort_kernel<<<NBUCK, 256, 0, stream>>>(bbase, staging, csr4, rowptr);

    int aggGrid = (NROWS * 64) / 256 + 1;
    agg_kernel<<<aggGrid, 256, 0, stream>>>(u0b, i0b, u1b, i1b, di, dj, rowptr, csr4);
    agg_kernel<<<aggGrid, 256, 0, stream>>>(u1b, i1b, u2b, i2b, di, dj, rowptr, csr4);
    agg_kernel<<<aggGrid, 256, 0, stream>>>(u2b, i2b, u3b, i3b, di, dj, rowptr, csr4);

    batch_kernel<<<(BATCH * 64) / 256, 256, 0, stream>>>(u0f, i0f, u1b, u2b, u3b,
                                                         i1b, i2b, i3b,
                                                         usr, ita, itb, out, ls, l2a);
    final_kernel<<<1, 256, 0, stream>>>(ls, l2a, out);
}

// Round 17
// 596.257 us; speedup vs baseline: 1.0137x; 1.0137x over previous
//
#include <hip/hip_runtime.h>

#define U_NUM   100000
#define I_NUM   50000
#define FCT     64
#define NEDGE   3200000
#define BATCH   16384
#define NROWS   (U_NUM + I_NUM)      // 150000
#define TOTSLOTS (2 * NEDGE)         // 6400000

#define BSH 6                        // 64 rows per bucket
#define NBU 1563                     // ceil(100000/64)
#define NBI 782                      // ceil(50000/64)
#define NBUCK (NBU + NBI)            // 2345
#define NQ   294                     // ceil(NBUCK/8) buckets per class
#define SUBS 256                     // slices
#define BUFSZ 4096                   // LDS payload slots (expected fill 3125)

__device__ __forceinline__ unsigned short f2b(float f) {
    unsigned int x = __float_as_uint(f);
    unsigned int r = (x + 0x7FFFu + ((x >> 16) & 1u)) >> 16;   // RNE
    return (unsigned short)r;
}
__device__ __forceinline__ float b2f(unsigned short u) {
    return __uint_as_float(((unsigned int)u) << 16);
}

// ---------------- fp32 -> bf16 table conversion ----------------
__global__ void conv_kernel(const float* __restrict__ in, unsigned short* __restrict__ out, int n4) {
    int t = blockIdx.x * blockDim.x + threadIdx.x;
    if (t >= n4) return;
    float4 v = *reinterpret_cast<const float4*>(in + (size_t)t * 4);
    ushort4 o;
    o.x = f2b(v.x); o.y = f2b(v.y); o.z = f2b(v.z); o.w = f2b(v.w);
    *reinterpret_cast<ushort4*>(out + (size_t)t * 4) = o;
}

// ---------------- single-sweep per-(sub,bucket) count ----------------
__global__ void __launch_bounds__(256) count256_kernel(const int* __restrict__ eu,
                                                       const int* __restrict__ ei,
                                                       int* __restrict__ cntmat256) {
    __shared__ int lcnt[NBUCK];
    for (int k = threadIdx.x; k < NBUCK; k += 256) lcnt[k] = 0;
    __syncthreads();
    int sub = blockIdx.x;
    for (int t = sub * 256 + (int)threadIdx.x; t < NEDGE; t += SUBS * 256) {
        int u = eu[t];
        int i = ei[t];
        atomicAdd(&lcnt[u >> BSH], 1);
        atomicAdd(&lcnt[NBU + (i >> BSH)], 1);
    }
    __syncthreads();
    int* row = cntmat256 + (size_t)sub * NBUCK;
    for (int k = threadIdx.x; k < NBUCK; k += 256) row[k] = lcnt[k];
}

// ---------------- per-bucket scan over 256 subs -> localpfx + bucket total ----------------
__global__ void __launch_bounds__(256) bscan2_kernel(const int* __restrict__ cntmat256,
                                                     int* __restrict__ localpfx,
                                                     int* __restrict__ btot) {
    __shared__ int ws[4];
    int b = blockIdx.x;
    int t = threadIdx.x;
    int c = cntmat256[(size_t)t * NBUCK + b];
    int inc = c;
#pragma unroll
    for (int o = 1; o < 64; o <<= 1) {
        int x = __shfl_up(inc, o);
        if ((t & 63) >= o) inc += x;
    }
    if ((t & 63) == 63) ws[t >> 6] = inc;
    __syncthreads();
    int carry = 0;
#pragma unroll
    for (int w = 0; w < 4; w++) {
        if ((t >> 6) > w) carry += ws[w];
    }
    localpfx[(size_t)b * 256 + t] = carry + inc - c;   // exclusive prefix within bucket
    if (t == 255) btot[b] = carry + inc;               // bucket total
}

// ---------------- single-block exclusive scan over bucket totals -> bbase ----------------
__global__ void bscan_kernel(const int* __restrict__ btot, int* __restrict__ bbase) {
    __shared__ int s[256];
    int t = threadIdx.x;
    int v[10];                          // 256*10 = 2560 >= NBUCK
    int tot = 0;
#pragma unroll
    for (int k = 0; k < 10; k++) {
        int idx = t * 10 + k;
        v[k] = (idx < NBUCK) ? btot[idx] : 0;
        tot += v[k];
    }
    s[t] = tot;
    __syncthreads();
    for (int off = 1; off < 256; off <<= 1) {
        int x = (t >= off) ? s[t - off] : 0;
        __syncthreads();
        s[t] += x;
        __syncthreads();
    }
    int p = s[t] - tot;
#pragma unroll
    for (int k = 0; k < 10; k++) {
        int idx = t * 10 + k;
        if (idx < NBUCK) bbase[idx] = p;
        p += v[k];
    }
    if (t == 255) bbase[NBUCK] = TOTSLOTS;
}

// ---------------- multisplit scatter: 8 classes, SPLIT 5-byte payload ----------------
// staging4[slot] = (src:17 << 15) | bf16(val):15  (final csr4 format, pre-packed)
// staging_off[slot] = row offset in bucket (6 bits).
// LDS: 4+1 B/slot -> ~24 KB total -> ~6 blocks/CU (vs 36 KB / 4 blocks at int2).
__global__ void __launch_bounds__(256) scatterB_kernel(const int* __restrict__ eu,
                                                       const int* __restrict__ ei,
                                                       const float* __restrict__ vui,
                                                       const float* __restrict__ viu,
                                                       const int* __restrict__ cntmat256,
                                                       const int* __restrict__ localpfx,
                                                       const int* __restrict__ bbase,
                                                       unsigned int* __restrict__ staging4,
                                                       unsigned char* __restrict__ staging_off) {
    __shared__ int lofs[NQ + 1];
    __shared__ int lbase[NQ];
    __shared__ int lrank[NQ];
    __shared__ unsigned int lbuf4[BUFSZ];       // 16 KB
    __shared__ unsigned char lbufo[BUFSZ];      // 4 KB
    int cls = blockIdx.x & 7;
    int sub = blockIdx.x >> 3;
    for (int k = threadIdx.x; k < NQ; k += 256) {
        int b = k * 8 + cls;
        if (b < NBUCK) {
            lbase[k] = bbase[b] + localpfx[(size_t)b * 256 + sub];
            lofs[k + 1] = cntmat256[(size_t)sub * NBUCK + b];
        } else {
            lbase[k] = 0;
            lofs[k + 1] = 0;
        }
        lrank[k] = 0;
    }
    if (threadIdx.x == 0) lofs[0] = 0;
    __syncthreads();
    // wave 0: inclusive scan of lofs[1..NQ] (5 chunks of 64, carried)
    if (threadIdx.x < 64) {
        int carry = 0;
        for (int c = 0; c < 5; c++) {
            int idx = c * 64 + (int)threadIdx.x + 1;
            int v = (idx <= NQ) ? lofs[idx] : 0;
            int inc = v;
#pragma unroll
            for (int o = 1; o < 64; o <<= 1) {
                int x = __shfl_up(inc, o);
                if ((int)threadIdx.x >= o) inc += x;
            }
            if (idx <= NQ) lofs[idx] = carry + inc;
            carry += __shfl(inc, 63);
        }
    }
    __syncthreads();
    int total = lofs[NQ];
    for (int t = sub * 256 + (int)threadIdx.x; t < NEDGE; t += SUBS * 256) {
        int u = eu[t];
        int i = ei[t];
        int bu = u >> BSH;
        if ((bu & 7) == cls) {
            int q = bu >> 3;
            int r = atomicAdd(&lrank[q], 1);
            unsigned int pay = ((unsigned int)i << 15) | ((unsigned int)f2b(vui[t]) & 0x7FFFu);
            unsigned char off = (unsigned char)(u & 63);
            int pos = lofs[q] + r;
            if (pos < BUFSZ) { lbuf4[pos] = pay; lbufo[pos] = off; }
            else { staging4[lbase[q] + r] = pay; staging_off[lbase[q] + r] = off; }
        }
        int bid = NBU + (i >> BSH);
        if ((bid & 7) == cls) {
            int q = bid >> 3;
            int r = atomicAdd(&lrank[q], 1);
            unsigned int pay = ((unsigned int)u << 15) | ((unsigned int)f2b(viu[t]) & 0x7FFFu);
            unsigned char off = (unsigned char)(i & 63);
            int pos = lofs[q] + r;
            if (pos < BUFSZ) { lbuf4[pos] = pay; lbufo[pos] = off; }
            else { staging4[lbase[q] + r] = pay; staging_off[lbase[q] + r] = off; }
        }
    }
    __syncthreads();
    // coalesced flush: flat t -> bucket via binary search on lofs
    int fl = min(total, BUFSZ);
    for (int t = threadIdx.x; t < fl; t += 256) {
        int lo = 0, hi = NQ;
        while (hi - lo > 1) {
            int mid = (lo + hi) >> 1;
            if (lofs[mid] <= t) lo = mid; else hi = mid;
        }
        int g = lbase[lo] + (t - lofs[lo]);
        staging4[g] = lbuf4[t];
        staging_off[g] = lbufo[t];
    }
}

// ---------------- phase B: row counts -> rowptr -> row-ordered csr (direct copy) ----------------
__global__ void __launch_bounds__(256) rsort_kernel(const int* __restrict__ bbase,
                                                    const unsigned int* __restrict__ staging4,
                                                    const unsigned char* __restrict__ staging_off,
                                                    unsigned int* __restrict__ csr4,
                                                    int* __restrict__ rowptr) {
    __shared__ int fillr[64];
    __shared__ int rp[64];
    int b = blockIdx.x;
    int gRowBase, rows;
    if (b < NBU) {
        gRowBase = b << BSH;
        rows = min(64, U_NUM - gRowBase);
    } else {
        int rb = (b - NBU) << BSH;
        gRowBase = U_NUM + rb;
        rows = min(64, I_NUM - rb);
    }
    if (threadIdx.x < 64) fillr[threadIdx.x] = 0;
    __syncthreads();
    int beg = bbase[b], end = bbase[b + 1];
    // pass 1: per-row counts from the 1-byte off array only (6.4 MB total, was 51.2)
    for (int e = beg + (int)threadIdx.x; e < end; e += 256) {
        atomicAdd(&fillr[staging_off[e]], 1);
    }
    __syncthreads();
    if (threadIdx.x < 64) {
        int c = fillr[threadIdx.x];
        int inc = c;
#pragma unroll
        for (int o = 1; o < 64; o <<= 1) {
            int x = __shfl_up(inc, o);
            if ((int)threadIdx.x >= o) inc += x;
        }
        int excl = beg + inc - c;
        rp[threadIdx.x] = excl;
        if ((int)threadIdx.x < rows) rowptr[gRowBase + threadIdx.x] = excl;
        fillr[threadIdx.x] = 0;
    }
    if (b == 0 && threadIdx.x == 64) rowptr[NROWS] = TOTSLOTS;
    __syncthreads();
    // pass 2: scatter pre-packed payload to row-ordered csr
    for (int e = beg + (int)threadIdx.x; e < end; e += 256) {
        int off = staging_off[e];
        int dst = rp[off] + atomicAdd(&fillr[off], 1);
        csr4[dst] = staging4[e];
    }
}

// ---------------- propagation: half-wave per edge, ushort2 (uint) packed lanes ----------------
__global__ void __launch_bounds__(256) agg_kernel(
        const unsigned short* __restrict__ uprev, const unsigned short* __restrict__ iprev,
        unsigned short* __restrict__ unext, unsigned short* __restrict__ inext,
        const float* __restrict__ di, const float* __restrict__ dj,
        const int* __restrict__ rowptr, const unsigned int* __restrict__ csr4) {
    int wid = (blockIdx.x * 256 + threadIdx.x) >> 6;
    int lane = threadIdx.x & 63;
    if (wid >= NROWS) return;
    int half = lane >> 5;
    unsigned int dp = (unsigned int)(lane & 31);   // dim-pair index
    const unsigned int* selfU;
    const unsigned int* srcU;
    unsigned int* dstU;
    float dscale;
    unsigned int r32;
    if (wid < U_NUM) {
        r32 = (unsigned int)wid;
        selfU = (const unsigned int*)uprev;
        srcU  = (const unsigned int*)iprev;
        dstU  = (unsigned int*)unext;
        dscale = di[wid];
    } else {
        r32 = (unsigned int)(wid - U_NUM);
        selfU = (const unsigned int*)iprev;
        srcU  = (const unsigned int*)uprev;
        dstU  = (unsigned int*)inext;
        dscale = dj[wid - U_NUM];
    }
    int beg = rowptr[wid], end = rowptr[wid + 1];
    unsigned int selfIdx = (r32 << 5) | dp;
    float accx, accy;
    {
        unsigned int s = selfU[selfIdx];
        float sx = b2f((unsigned short)(s & 0xFFFFu));
        float sy = b2f((unsigned short)(s >> 16));
        accx = (half == 0) ? sx * dscale : 0.0f;
        accy = (half == 0) ? sy * dscale : 0.0f;
    }
    int e = beg;
    for (; e + 8 <= end; e += 8) {
        unsigned int pk[4], g[4];
#pragma unroll
        for (int k = 0; k < 4; k++) pk[k] = csr4[e + 2 * k + half];
#pragma unroll
        for (int k = 0; k < 4; k++) g[k] = srcU[((pk[k] >> 15) << 5) | dp];
#pragma unroll
        for (int k = 0; k < 4; k++) {
            float w = b2f((unsigned short)(pk[k] & 0x7FFFu));
            accx = fmaf(w, b2f((unsigned short)(g[k] & 0xFFFFu)), accx);
            accy = fmaf(w, b2f((unsigned short)(g[k] >> 16)), accy);
        }
    }
    for (; e < end; e += 2) {
        int idx = e + half;
        if (idx < end) {
            unsigned int pk = csr4[idx];
            unsigned int g = srcU[((pk >> 15) << 5) | dp];
            float w = b2f((unsigned short)(pk & 0x7FFFu));
            accx = fmaf(w, b2f((unsigned short)(g & 0xFFFFu)), accx);
            accy = fmaf(w, b2f((unsigned short)(g >> 16)), accy);
        }
    }
    accx += __shfl_xor(accx, 32);
    accy += __shfl_xor(accy, 32);
    if (half == 0) {
        unsigned int o = ((unsigned int)f2b(accy) << 16) | (unsigned int)f2b(accx);
        dstU[selfIdx] = o;
    }
}

// ---------------- BPR head ----------------
__global__ void __launch_bounds__(256) batch_kernel(
        const float* __restrict__ u0f, const float* __restrict__ i0f,
        const unsigned short* __restrict__ u1, const unsigned short* __restrict__ u2,
        const unsigned short* __restrict__ u3,
        const unsigned short* __restrict__ i1, const unsigned short* __restrict__ i2,
        const unsigned short* __restrict__ i3,
        const int* __restrict__ user, const int* __restrict__ ita, const int* __restrict__ itb,
        float* __restrict__ out, float* __restrict__ ls, float* __restrict__ l2a) {
    int wid = (blockIdx.x * 256 + threadIdx.x) >> 6;
    int lane = threadIdx.x & 63;
    if (wid >= BATCH) return;
    size_t uo = (size_t)user[wid] * FCT + lane;
    size_t ao = (size_t)ita[wid] * FCT + lane;
    size_t bo = (size_t)itb[wid] * FCT + lane;

    float pi, pj, l2;
    {
        float ue = u0f[uo], ie = i0f[ao], je = i0f[bo];
        pi = ue * ie; pj = ue * je; l2 = ue * ue + ie * ie + je * je;
    }
    const unsigned short* Ut[3] = {u1, u2, u3};
    const unsigned short* It[3] = {i1, i2, i3};
#pragma unroll
    for (int l = 0; l < 3; l++) {
        float ue = b2f(Ut[l][uo]), ie = b2f(It[l][ao]), je = b2f(It[l][bo]);
        pi += ue * ie;
        pj += ue * je;
        l2 += ue * ue + ie * ie + je * je;
    }
#pragma unroll
    for (int off = 32; off; off >>= 1) {
        pi += __shfl_xor(pi, off);
        pj += __shfl_xor(pj, off);
        l2 += __shfl_xor(l2, off);
    }
    if (lane == 0) {
        out[wid] = pi;
        out[BATCH + wid] = pj;
        float x = pi - pj;
        ls[wid] = fminf(x, 0.0f) - log1pf(expf(-fabsf(x)));
        l2a[wid] = 0.01f * l2;
    }
}

__global__ void final_kernel(const float* __restrict__ ls, const float* __restrict__ l2a,
                             float* __restrict__ out) {
    __shared__ float s1[256], s2[256];
    int t = threadIdx.x;
    float a = 0.f, b = 0.f;
    for (int i = t; i < BATCH; i += 256) {
        a += ls[i];
        b += l2a[i];
    }
    s1[t] = a;
    s2[t] = b;
    __syncthreads();
    for (int off = 128; off; off >>= 1) {
        if (t < off) {
            s1[t] += s1[t + off];
            s2[t] += s2[t + off];
        }
        __syncthreads();
    }
    if (t == 0) {
        float loss2 = -s1[0] / (float)BATCH;
        float l2m = s2[0] / (float)BATCH;
        out[2 * BATCH] = loss2 + l2m;
        out[2 * BATCH + 1] = loss2;
    }
}

// ---------------- launch ----------------
extern "C" void kernel_launch(void* const* d_in, const int* in_sizes, int n_in,
                              void* d_out, int out_size, void* d_ws, size_t ws_size,
                              hipStream_t stream) {
    const float* u0f = (const float*)d_in[0];
    const float* i0f = (const float*)d_in[1];
    const float* di  = (const float*)d_in[2];
    const float* dj  = (const float*)d_in[3];
    const float* vui = (const float*)d_in[4];
    const float* viu = (const float*)d_in[5];
    const int*   eu  = (const int*)d_in[6];
    const int*   ei  = (const int*)d_in[7];
    const int*   usr = (const int*)d_in[8];
    const int*   ita = (const int*)d_in[9];
    const int*   itb = (const int*)d_in[10];
    float* out = (float*)d_out;

    char* p = (char*)d_ws;
    auto alloc = [&](size_t bytes) -> char* {
        char* r = p;
        p += (bytes + 255) & ~(size_t)255;
        return r;
    };
    unsigned short* u0b = (unsigned short*)alloc((size_t)U_NUM * FCT * 2);
    unsigned short* u1b = (unsigned short*)alloc((size_t)U_NUM * FCT * 2);
    unsigned short* i0b = (unsigned short*)alloc((size_t)I_NUM * FCT * 2);
    unsigned short* i1b = (unsigned short*)alloc((size_t)I_NUM * FCT * 2);
    unsigned int* csr4        = (unsigned int*)alloc((size_t)TOTSLOTS * 4);   // 25.6 MB
    unsigned int* staging4    = (unsigned int*)alloc((size_t)TOTSLOTS * 4);   // 25.6 MB
    unsigned char* staging_off = (unsigned char*)alloc((size_t)TOTSLOTS);     // 6.4 MB
    unsigned short* i3b = (unsigned short*)alloc((size_t)I_NUM * FCT * 2);    // 6.4 MB
    int* rowptr    = (int*)alloc((size_t)(NROWS + 1) * 4);
    int* cntmat256 = (int*)alloc((size_t)SUBS * NBUCK * 4);            // 2.4 MB
    int* localpfx  = (int*)alloc((size_t)NBUCK * SUBS * 4);            // 2.4 MB
    int* btot      = (int*)alloc((size_t)NBUCK * 4);
    int* bbase     = (int*)alloc((size_t)(NBUCK + 1) * 4);
    float* ls      = (float*)alloc((size_t)BATCH * 4);
    float* l2a     = (float*)alloc((size_t)BATCH * 4);
    // overlay levels 2,3 on staging (dead after rsort; written by later agg launches):
    // u2b+u3b = 25.6 MB exactly overlays staging4; i2b = 6.4 MB exactly overlays staging_off.
    unsigned short* u2b = (unsigned short*)staging4;
    unsigned short* u3b = u2b + (size_t)U_NUM * FCT;
    unsigned short* i2b = (unsigned short*)staging_off;

    conv_kernel<<<(U_NUM * FCT / 4 + 255) / 256, 256, 0, stream>>>(u0f, u0b, U_NUM * FCT / 4);
    conv_kernel<<<(I_NUM * FCT / 4 + 255) / 256, 256, 0, stream>>>(i0f, i0b, I_NUM * FCT / 4);

    count256_kernel<<<SUBS, 256, 0, stream>>>(eu, ei, cntmat256);
    bscan2_kernel<<<NBUCK, 256, 0, stream>>>(cntmat256, localpfx, btot);
    bscan_kernel<<<1, 256, 0, stream>>>(btot, bbase);

    scatterB_kernel<<<SUBS * 8, 256, 0, stream>>>(eu, ei, vui, viu, cntmat256, localpfx,
                                                  bbase, staging4, staging_off);
    rsort_kernel<<<NBUCK, 256, 0, stream>>>(bbase, staging4, staging_off, csr4, rowptr);

    int aggGrid = (NROWS * 64) / 256 + 1;
    agg_kernel<<<aggGrid, 256, 0, stream>>>(u0b, i0b, u1b, i1b, di, dj, rowptr, csr4);
    agg_kernel<<<aggGrid, 256, 0, stream>>>(u1b, i1b, u2b, i2b, di, dj, rowptr, csr4);
    agg_kernel<<<aggGrid, 256, 0, stream>>>(u2b, i2b, u3b, i3b, di, dj, rowptr, csr4);

    batch_kernel<<<(BATCH * 64) / 256, 256, 0, stream>>>(u0f, i0f, u1b, u2b, u3b,
                                                         i1b, i2b, i3b,
                                                         usr, ita, itb, out, ls, l2a);
    final_kernel<<<1, 256, 0, stream>>>(ls, l2a, out);
}

// Round 18
// 550.727 us; speedup vs baseline: 1.0975x; 1.0827x over previous
//
#include <hip/hip_runtime.h>

#define U_NUM   100000
#define I_NUM   50000
#define FCT     64
#define NEDGE   3200000
#define BATCH   16384
#define NROWS   (U_NUM + I_NUM)      // 150000
#define TOTSLOTS (2 * NEDGE)         // 6400000

#define BSH 6                        // 64 rows per bucket
#define NBU 1563                     // ceil(100000/64)
#define NBI 782                      // ceil(50000/64)
#define NBUCK (NBU + NBI)            // 2345
#define NQ   294                     // ceil(NBUCK/8) buckets per class
#define SUBS 256                     // slices
#define BUFSZ 4096                   // LDS payload slots (expected fill 3125)

__device__ __forceinline__ unsigned short f2b(float f) {
    unsigned int x = __float_as_uint(f);
    unsigned int r = (x + 0x7FFFu + ((x >> 16) & 1u)) >> 16;   // RNE
    return (unsigned short)r;
}
__device__ __forceinline__ float b2f(unsigned short u) {
    return __uint_as_float(((unsigned int)u) << 16);
}

// ---------------- fp32 -> bf16 table conversion ----------------
__global__ void conv_kernel(const float* __restrict__ in, unsigned short* __restrict__ out, int n4) {
    int t = blockIdx.x * blockDim.x + threadIdx.x;
    if (t >= n4) return;
    float4 v = *reinterpret_cast<const float4*>(in + (size_t)t * 4);
    ushort4 o;
    o.x = f2b(v.x); o.y = f2b(v.y); o.z = f2b(v.z); o.w = f2b(v.w);
    *reinterpret_cast<ushort4*>(out + (size_t)t * 4) = o;
}

// ---------------- single-sweep per-(sub,bucket) count ----------------
__global__ void __launch_bounds__(256) count256_kernel(const int* __restrict__ eu,
                                                       const int* __restrict__ ei,
                                                       int* __restrict__ cntmat256) {
    __shared__ int lcnt[NBUCK];
    for (int k = threadIdx.x; k < NBUCK; k += 256) lcnt[k] = 0;
    __syncthreads();
    int sub = blockIdx.x;
    for (int t = sub * 256 + (int)threadIdx.x; t < NEDGE; t += SUBS * 256) {
        int u = eu[t];
        int i = ei[t];
        atomicAdd(&lcnt[u >> BSH], 1);
        atomicAdd(&lcnt[NBU + (i >> BSH)], 1);
    }
    __syncthreads();
    int* row = cntmat256 + (size_t)sub * NBUCK;
    for (int k = threadIdx.x; k < NBUCK; k += 256) row[k] = lcnt[k];
}

// ---------------- per-bucket scan over 256 subs -> localpfx + bucket total ----------------
__global__ void __launch_bounds__(256) bscan2_kernel(const int* __restrict__ cntmat256,
                                                     int* __restrict__ localpfx,
                                                     int* __restrict__ btot) {
    __shared__ int ws[4];
    int b = blockIdx.x;
    int t = threadIdx.x;
    int c = cntmat256[(size_t)t * NBUCK + b];
    int inc = c;
#pragma unroll
    for (int o = 1; o < 64; o <<= 1) {
        int x = __shfl_up(inc, o);
        if ((t & 63) >= o) inc += x;
    }
    if ((t & 63) == 63) ws[t >> 6] = inc;
    __syncthreads();
    int carry = 0;
#pragma unroll
    for (int w = 0; w < 4; w++) {
        if ((t >> 6) > w) carry += ws[w];
    }
    localpfx[(size_t)b * 256 + t] = carry + inc - c;   // exclusive prefix within bucket
    if (t == 255) btot[b] = carry + inc;               // bucket total
}

// ---------------- single-block exclusive scan over bucket totals -> bbase ----------------
__global__ void bscan_kernel(const int* __restrict__ btot, int* __restrict__ bbase) {
    __shared__ int s[256];
    int t = threadIdx.x;
    int v[10];                          // 256*10 = 2560 >= NBUCK
    int tot = 0;
#pragma unroll
    for (int k = 0; k < 10; k++) {
        int idx = t * 10 + k;
        v[k] = (idx < NBUCK) ? btot[idx] : 0;
        tot += v[k];
    }
    s[t] = tot;
    __syncthreads();
    for (int off = 1; off < 256; off <<= 1) {
        int x = (t >= off) ? s[t - off] : 0;
        __syncthreads();
        s[t] += x;
        __syncthreads();
    }
    int p = s[t] - tot;
#pragma unroll
    for (int k = 0; k < 10; k++) {
        int idx = t * 10 + k;
        if (idx < NBUCK) bbase[idx] = p;
        p += v[k];
    }
    if (t == 255) bbase[NBUCK] = TOTSLOTS;
}

// ---------------- per-(sub,cls) totals from cntmat256 ----------------
__global__ void __launch_bounds__(256) csum_kernel(const int* __restrict__ cntmat256,
                                                   int* __restrict__ csum) {
    int gid = blockIdx.x * 256 + threadIdx.x;   // 0..2047, sub-major: gid = sub*8+cls
    int sub = gid >> 3, cls = gid & 7;
    const int* row = cntmat256 + (size_t)sub * NBUCK;
    int s = 0;
    for (int q = 0; q < NQ; q++) {
        int b = q * 8 + cls;
        if (b < NBUCK) s += row[b];
    }
    csum[gid] = s;
}

// ---------------- exclusive scan over 2048 (sub,cls) totals -> cbase ----------------
__global__ void cbase_kernel(const int* __restrict__ csum, int* __restrict__ cbase) {
    __shared__ int s[256];
    int t = threadIdx.x;
    int v[8];
    int tot = 0;
#pragma unroll
    for (int k = 0; k < 8; k++) {
        v[k] = csum[t * 8 + k];
        tot += v[k];
    }
    s[t] = tot;
    __syncthreads();
    for (int off = 1; off < 256; off <<= 1) {
        int x = (t >= off) ? s[t - off] : 0;
        __syncthreads();
        s[t] += x;
        __syncthreads();
    }
    int p = s[t] - tot;
#pragma unroll
    for (int k = 0; k < 8; k++) {
        cbase[t * 8 + k] = p;
        p += v[k];
    }
    if (t == 255) cbase[2048] = TOTSLOTS;
}

// ---------------- phase A: 1x sweep, compact edges into per-(sub,cls) regions ----------------
// compact4[pos] = (src:17 << 15) | bf16(val):15   (final csr4 payload, pre-packed)
// compactA[pos] = (q:9 << 6) | off:6              (bucket-in-class + row offset)
// Appends are sequential per region (LDS rank counters) -> ~16 frontier lines/block,
// write amp ~1x. Each region has a single writer block.
__global__ void __launch_bounds__(256) cscatA_kernel(const int* __restrict__ eu,
                                                     const int* __restrict__ ei,
                                                     const float* __restrict__ vui,
                                                     const float* __restrict__ viu,
                                                     const int* __restrict__ cbase,
                                                     unsigned int* __restrict__ compact4,
                                                     unsigned short* __restrict__ compactA) {
    __shared__ int lbase8[8];
    __shared__ int lcnt8[8];
    int sub = blockIdx.x;
    if (threadIdx.x < 8) {
        lbase8[threadIdx.x] = cbase[sub * 8 + (int)threadIdx.x];
        lcnt8[threadIdx.x] = 0;
    }
    __syncthreads();
    for (int t = sub * 256 + (int)threadIdx.x; t < NEDGE; t += SUBS * 256) {
        int u = eu[t];
        int i = ei[t];
        float va = vui[t];
        float vb = viu[t];
        // user-destination half: src = i, val = vui
        int bu = u >> BSH;
        int cls = bu & 7;
        int r = atomicAdd(&lcnt8[cls], 1);
        int pos = lbase8[cls] + r;
        compact4[pos] = ((unsigned int)i << 15) | ((unsigned int)f2b(va) & 0x7FFFu);
        compactA[pos] = (unsigned short)((((unsigned int)(bu >> 3)) << 6) | (unsigned int)(u & 63));
        // item-destination half: src = u, val = viu
        int bid = NBU + (i >> BSH);
        int cls2 = bid & 7;
        int r2 = atomicAdd(&lcnt8[cls2], 1);
        int pos2 = lbase8[cls2] + r2;
        compact4[pos2] = ((unsigned int)u << 15) | ((unsigned int)f2b(vb) & 0x7FFFu);
        compactA[pos2] = (unsigned short)((((unsigned int)(bid >> 3)) << 6) | (unsigned int)(i & 63));
    }
}

// ---------------- phase B: per-(cls,sub) region -> bucket-ordered staging ----------------
__global__ void __launch_bounds__(256) scatterC_kernel(const unsigned int* __restrict__ compact4,
                                                       const unsigned short* __restrict__ compactA,
                                                       const int* __restrict__ cntmat256,
                                                       const int* __restrict__ localpfx,
                                                       const int* __restrict__ bbase,
                                                       const int* __restrict__ cbase,
                                                       unsigned int* __restrict__ staging4,
                                                       unsigned char* __restrict__ staging_off) {
    __shared__ int lofs[NQ + 1];
    __shared__ int lbase[NQ];
    __shared__ int lrank[NQ];
    __shared__ unsigned int lbuf4[BUFSZ];       // 16 KB
    __shared__ unsigned char lbufo[BUFSZ];      // 4 KB
    int cls = blockIdx.x & 7;
    int sub = blockIdx.x >> 3;
    for (int k = threadIdx.x; k < NQ; k += 256) {
        int b = k * 8 + cls;
        if (b < NBUCK) {
            lbase[k] = bbase[b] + localpfx[(size_t)b * 256 + sub];
            lofs[k + 1] = cntmat256[(size_t)sub * NBUCK + b];
        } else {
            lbase[k] = 0;
            lofs[k + 1] = 0;
        }
        lrank[k] = 0;
    }
    if (threadIdx.x == 0) lofs[0] = 0;
    __syncthreads();
    // wave 0: inclusive scan of lofs[1..NQ] (5 chunks of 64, carried)
    if (threadIdx.x < 64) {
        int carry = 0;
        for (int c = 0; c < 5; c++) {
            int idx = c * 64 + (int)threadIdx.x + 1;
            int v = (idx <= NQ) ? lofs[idx] : 0;
            int inc = v;
#pragma unroll
            for (int o = 1; o < 64; o <<= 1) {
                int x = __shfl_up(inc, o);
                if ((int)threadIdx.x >= o) inc += x;
            }
            if (idx <= NQ) lofs[idx] = carry + inc;
            carry += __shfl(inc, 63);
        }
    }
    __syncthreads();
    int total = lofs[NQ];
    int rbeg = cbase[sub * 8 + cls], rend = cbase[sub * 8 + cls + 1];
    for (int e = rbeg + (int)threadIdx.x; e < rend; e += 256) {
        unsigned int pay = compact4[e];
        unsigned int a = compactA[e];
        int q = (int)(a >> 6);
        unsigned char off = (unsigned char)(a & 63u);
        int r = atomicAdd(&lrank[q], 1);
        int pos = lofs[q] + r;
        if (pos < BUFSZ) { lbuf4[pos] = pay; lbufo[pos] = off; }
        else { staging4[lbase[q] + r] = pay; staging_off[lbase[q] + r] = off; }
    }
    __syncthreads();
    // coalesced flush: flat t -> bucket via binary search on lofs
    int fl = min(total, BUFSZ);
    for (int t = threadIdx.x; t < fl; t += 256) {
        int lo = 0, hi = NQ;
        while (hi - lo > 1) {
            int mid = (lo + hi) >> 1;
            if (lofs[mid] <= t) lo = mid; else hi = mid;
        }
        int g = lbase[lo] + (t - lofs[lo]);
        staging4[g] = lbuf4[t];
        staging_off[g] = lbufo[t];
    }
}

// ---------------- phase C: row counts -> rowptr -> row-ordered csr (direct copy) ----------------
__global__ void __launch_bounds__(256) rsort_kernel(const int* __restrict__ bbase,
                                                    const unsigned int* __restrict__ staging4,
                                                    const unsigned char* __restrict__ staging_off,
                                                    unsigned int* __restrict__ csr4,
                                                    int* __restrict__ rowptr) {
    __shared__ int fillr[64];
    __shared__ int rp[64];
    int b = blockIdx.x;
    int gRowBase, rows;
    if (b < NBU) {
        gRowBase = b << BSH;
        rows = min(64, U_NUM - gRowBase);
    } else {
        int rb = (b - NBU) << BSH;
        gRowBase = U_NUM + rb;
        rows = min(64, I_NUM - rb);
    }
    if (threadIdx.x < 64) fillr[threadIdx.x] = 0;
    __syncthreads();
    int beg = bbase[b], end = bbase[b + 1];
    for (int e = beg + (int)threadIdx.x; e < end; e += 256) {
        atomicAdd(&fillr[staging_off[e]], 1);
    }
    __syncthreads();
    if (threadIdx.x < 64) {
        int c = fillr[threadIdx.x];
        int inc = c;
#pragma unroll
        for (int o = 1; o < 64; o <<= 1) {
            int x = __shfl_up(inc, o);
            if ((int)threadIdx.x >= o) inc += x;
        }
        int excl = beg + inc - c;
        rp[threadIdx.x] = excl;
        if ((int)threadIdx.x < rows) rowptr[gRowBase + threadIdx.x] = excl;
        fillr[threadIdx.x] = 0;
    }
    if (b == 0 && threadIdx.x == 64) rowptr[NROWS] = TOTSLOTS;
    __syncthreads();
    for (int e = beg + (int)threadIdx.x; e < end; e += 256) {
        int off = staging_off[e];
        int dst = rp[off] + atomicAdd(&fillr[off], 1);
        csr4[dst] = staging4[e];
    }
}

// ---------------- propagation: half-wave per edge, ushort2 (uint) packed lanes ----------------
__global__ void __launch_bounds__(256) agg_kernel(
        const unsigned short* __restrict__ uprev, const unsigned short* __restrict__ iprev,
        unsigned short* __restrict__ unext, unsigned short* __restrict__ inext,
        const float* __restrict__ di, const float* __restrict__ dj,
        const int* __restrict__ rowptr, const unsigned int* __restrict__ csr4) {
    int wid = (blockIdx.x * 256 + threadIdx.x) >> 6;
    int lane = threadIdx.x & 63;
    if (wid >= NROWS) return;
    int half = lane >> 5;
    unsigned int dp = (unsigned int)(lane & 31);   // dim-pair index
    const unsigned int* selfU;
    const unsigned int* srcU;
    unsigned int* dstU;
    float dscale;
    unsigned int r32;
    if (wid < U_NUM) {
        r32 = (unsigned int)wid;
        selfU = (const unsigned int*)uprev;
        srcU  = (const unsigned int*)iprev;
        dstU  = (unsigned int*)unext;
        dscale = di[wid];
    } else {
        r32 = (unsigned int)(wid - U_NUM);
        selfU = (const unsigned int*)iprev;
        srcU  = (const unsigned int*)uprev;
        dstU  = (unsigned int*)inext;
        dscale = dj[wid - U_NUM];
    }
    int beg = rowptr[wid], end = rowptr[wid + 1];
    unsigned int selfIdx = (r32 << 5) | dp;
    float accx, accy;
    {
        unsigned int s = selfU[selfIdx];
        float sx = b2f((unsigned short)(s & 0xFFFFu));
        float sy = b2f((unsigned short)(s >> 16));
        accx = (half == 0) ? sx * dscale : 0.0f;
        accy = (half == 0) ? sy * dscale : 0.0f;
    }
    int e = beg;
    for (; e + 8 <= end; e += 8) {
        unsigned int pk[4], g[4];
#pragma unroll
        for (int k = 0; k < 4; k++) pk[k] = csr4[e + 2 * k + half];
#pragma unroll
        for (int k = 0; k < 4; k++) g[k] = srcU[((pk[k] >> 15) << 5) | dp];
#pragma unroll
        for (int k = 0; k < 4; k++) {
            float w = b2f((unsigned short)(pk[k] & 0x7FFFu));
            accx = fmaf(w, b2f((unsigned short)(g[k] & 0xFFFFu)), accx);
            accy = fmaf(w, b2f((unsigned short)(g[k] >> 16)), accy);
        }
    }
    for (; e < end; e += 2) {
        int idx = e + half;
        if (idx < end) {
            unsigned int pk = csr4[idx];
            unsigned int g = srcU[((pk >> 15) << 5) | dp];
            float w = b2f((unsigned short)(pk & 0x7FFFu));
            accx = fmaf(w, b2f((unsigned short)(g & 0xFFFFu)), accx);
            accy = fmaf(w, b2f((unsigned short)(g >> 16)), accy);
        }
    }
    accx += __shfl_xor(accx, 32);
    accy += __shfl_xor(accy, 32);
    if (half == 0) {
        unsigned int o = ((unsigned int)f2b(accy) << 16) | (unsigned int)f2b(accx);
        dstU[selfIdx] = o;
    }
}

// ---------------- BPR head ----------------
__global__ void __launch_bounds__(256) batch_kernel(
        const float* __restrict__ u0f, const float* __restrict__ i0f,
        const unsigned short* __restrict__ u1, const unsigned short* __restrict__ u2,
        const unsigned short* __restrict__ u3,
        const unsigned short* __restrict__ i1, const unsigned short* __restrict__ i2,
        const unsigned short* __restrict__ i3,
        const int* __restrict__ user, const int* __restrict__ ita, const int* __restrict__ itb,
        float* __restrict__ out, float* __restrict__ ls, float* __restrict__ l2a) {
    int wid = (blockIdx.x * 256 + threadIdx.x) >> 6;
    int lane = threadIdx.x & 63;
    if (wid >= BATCH) return;
    size_t uo = (size_t)user[wid] * FCT + lane;
    size_t ao = (size_t)ita[wid] * FCT + lane;
    size_t bo = (size_t)itb[wid] * FCT + lane;

    float pi, pj, l2;
    {
        float ue = u0f[uo], ie = i0f[ao], je = i0f[bo];
        pi = ue * ie; pj = ue * je; l2 = ue * ue + ie * ie + je * je;
    }
    const unsigned short* Ut[3] = {u1, u2, u3};
    const unsigned short* It[3] = {i1, i2, i3};
#pragma unroll
    for (int l = 0; l < 3; l++) {
        float ue = b2f(Ut[l][uo]), ie = b2f(It[l][ao]), je = b2f(It[l][bo]);
        pi += ue * ie;
        pj += ue * je;
        l2 += ue * ue + ie * ie + je * je;
    }
#pragma unroll
    for (int off = 32; off; off >>= 1) {
        pi += __shfl_xor(pi, off);
        pj += __shfl_xor(pj, off);
        l2 += __shfl_xor(l2, off);
    }
    if (lane == 0) {
        out[wid] = pi;
        out[BATCH + wid] = pj;
        float x = pi - pj;
        ls[wid] = fminf(x, 0.0f) - log1pf(expf(-fabsf(x)));
        l2a[wid] = 0.01f * l2;
    }
}

__global__ void final_kernel(const float* __restrict__ ls, const float* __restrict__ l2a,
                             float* __restrict__ out) {
    __shared__ float s1[256], s2[256];
    int t = threadIdx.x;
    float a = 0.f, b = 0.f;
    for (int i = t; i < BATCH; i += 256) {
        a += ls[i];
        b += l2a[i];
    }
    s1[t] = a;
    s2[t] = b;
    __syncthreads();
    for (int off = 128; off; off >>= 1) {
        if (t < off) {
            s1[t] += s1[t + off];
            s2[t] += s2[t + off];
        }
        __syncthreads();
    }
    if (t == 0) {
        float loss2 = -s1[0] / (float)BATCH;
        float l2m = s2[0] / (float)BATCH;
        out[2 * BATCH] = loss2 + l2m;
        out[2 * BATCH + 1] = loss2;
    }
}

// ---------------- launch ----------------
extern "C" void kernel_launch(void* const* d_in, const int* in_sizes, int n_in,
                              void* d_out, int out_size, void* d_ws, size_t ws_size,
                              hipStream_t stream) {
    const float* u0f = (const float*)d_in[0];
    const float* i0f = (const float*)d_in[1];
    const float* di  = (const float*)d_in[2];
    const float* dj  = (const float*)d_in[3];
    const float* vui = (const float*)d_in[4];
    const float* viu = (const float*)d_in[5];
    const int*   eu  = (const int*)d_in[6];
    const int*   ei  = (const int*)d_in[7];
    const int*   usr = (const int*)d_in[8];
    const int*   ita = (const int*)d_in[9];
    const int*   itb = (const int*)d_in[10];
    float* out = (float*)d_out;

    char* p = (char*)d_ws;
    auto alloc = [&](size_t bytes) -> char* {
        char* r = p;
        p += (bytes + 255) & ~(size_t)255;
        return r;
    };
    unsigned short* u0b = (unsigned short*)alloc((size_t)U_NUM * FCT * 2);
    unsigned short* u1b = (unsigned short*)alloc((size_t)U_NUM * FCT * 2);
    unsigned short* i0b = (unsigned short*)alloc((size_t)I_NUM * FCT * 2);
    unsigned short* i1b = (unsigned short*)alloc((size_t)I_NUM * FCT * 2);
    unsigned int* compact4   = (unsigned int*)alloc((size_t)TOTSLOTS * 4);    // 25.6 MB
    unsigned short* compactA = (unsigned short*)alloc((size_t)TOTSLOTS * 2);  // 12.8 MB
    unsigned int* staging4    = (unsigned int*)alloc((size_t)TOTSLOTS * 4);   // 25.6 MB
    unsigned char* staging_off = (unsigned char*)alloc((size_t)TOTSLOTS);     // 6.4 MB
    int* rowptr    = (int*)alloc((size_t)(NROWS + 1) * 4);
    int* cntmat256 = (int*)alloc((size_t)SUBS * NBUCK * 4);            // 2.4 MB
    int* localpfx  = (int*)alloc((size_t)NBUCK * SUBS * 4);            // 2.4 MB
    int* btot      = (int*)alloc((size_t)NBUCK * 4);
    int* bbase     = (int*)alloc((size_t)(NBUCK + 1) * 4);
    int* csum      = (int*)alloc((size_t)2048 * 4);
    int* cbase     = (int*)alloc((size_t)2049 * 4);
    float* ls      = (float*)alloc((size_t)BATCH * 4);
    float* l2a     = (float*)alloc((size_t)BATCH * 4);
    // overlays (disjoint lifetimes):
    //   csr4 <- compact4 (compact dead after scatterC; csr4 written in rsort)
    //   i3b  <- compactA (dead after scatterC; i3b written in agg stage 3)
    //   u2b,u3b <- staging4 ; i2b <- staging_off (staging dead after rsort)
    unsigned int* csr4 = compact4;
    unsigned short* i3b = compactA;
    unsigned short* u2b = (unsigned short*)staging4;
    unsigned short* u3b = u2b + (size_t)U_NUM * FCT;
    unsigned short* i2b = (unsigned short*)staging_off;

    conv_kernel<<<(U_NUM * FCT / 4 + 255) / 256, 256, 0, stream>>>(u0f, u0b, U_NUM * FCT / 4);
    conv_kernel<<<(I_NUM * FCT / 4 + 255) / 256, 256, 0, stream>>>(i0f, i0b, I_NUM * FCT / 4);

    count256_kernel<<<SUBS, 256, 0, stream>>>(eu, ei, cntmat256);
    bscan2_kernel<<<NBUCK, 256, 0, stream>>>(cntmat256, localpfx, btot);
    bscan_kernel<<<1, 256, 0, stream>>>(btot, bbase);
    csum_kernel<<<8, 256, 0, stream>>>(cntmat256, csum);
    cbase_kernel<<<1, 256, 0, stream>>>(csum, cbase);

    cscatA_kernel<<<SUBS, 256, 0, stream>>>(eu, ei, vui, viu, cbase, compact4, compactA);
    scatterC_kernel<<<SUBS * 8, 256, 0, stream>>>(compact4, compactA, cntmat256, localpfx,
                                                  bbase, cbase, staging4, staging_off);
    rsort_kernel<<<NBUCK, 256, 0, stream>>>(bbase, staging4, staging_off, csr4, rowptr);

    int aggGrid = (NROWS * 64) / 256 + 1;
    agg_kernel<<<aggGrid, 256, 0, stream>>>(u0b, i0b, u1b, i1b, di, dj, rowptr, csr4);
    agg_kernel<<<aggGrid, 256, 0, stream>>>(u1b, i1b, u2b, i2b, di, dj, rowptr, csr4);
    agg_kernel<<<aggGrid, 256, 0, stream>>>(u2b, i2b, u3b, i3b, di, dj, rowptr, csr4);

    batch_kernel<<<(BATCH * 64) / 256, 256, 0, stream>>>(u0f, i0f, u1b, u2b, u3b,
                                                         i1b, i2b, i3b,
                                                         usr, ita, itb, out, ls, l2a);
    final_kernel<<<1, 256, 0, stream>>>(ls, l2a, out);
}

// Round 19
// 528.617 us; speedup vs baseline: 1.1434x; 1.0418x over previous
//
#include <hip/hip_runtime.h>

#define U_NUM   100000
#define I_NUM   50000
#define FCT     64
#define NEDGE   3200000
#define BATCH   16384
#define NROWS   (U_NUM + I_NUM)      // 150000
#define TOTSLOTS (2 * NEDGE)         // 6400000

#define BSH 6                        // 64 rows per bucket
#define NBU 1563                     // ceil(100000/64)
#define NBI 782                      // ceil(50000/64)
#define NBUCK (NBU + NBI)            // 2345
#define NQ   294                     // ceil(NBUCK/8) buckets per class
#define SUBS 256                     // slices
#define BUFSZ 4096                   // LDS payload slots (expected fill 3125)

__device__ __forceinline__ unsigned short f2b(float f) {
    unsigned int x = __float_as_uint(f);
    unsigned int r = (x + 0x7FFFu + ((x >> 16) & 1u)) >> 16;   // RNE
    return (unsigned short)r;
}
__device__ __forceinline__ float b2f(unsigned short u) {
    return __uint_as_float(((unsigned int)u) << 16);
}

// ---------------- fp32 -> bf16 table conversion ----------------
__global__ void conv_kernel(const float* __restrict__ in, unsigned short* __restrict__ out, int n4) {
    int t = blockIdx.x * blockDim.x + threadIdx.x;
    if (t >= n4) return;
    float4 v = *reinterpret_cast<const float4*>(in + (size_t)t * 4);
    ushort4 o;
    o.x = f2b(v.x); o.y = f2b(v.y); o.z = f2b(v.z); o.w = f2b(v.w);
    *reinterpret_cast<ushort4*>(out + (size_t)t * 4) = o;
}

// ---------------- single-sweep per-(sub,bucket) count ----------------
__global__ void __launch_bounds__(256) count256_kernel(const int* __restrict__ eu,
                                                       const int* __restrict__ ei,
                                                       int* __restrict__ cntmat256) {
    __shared__ int lcnt[NBUCK];
    for (int k = threadIdx.x; k < NBUCK; k += 256) lcnt[k] = 0;
    __syncthreads();
    int sub = blockIdx.x;
    for (int t = sub * 256 + (int)threadIdx.x; t < NEDGE; t += SUBS * 256) {
        int u = eu[t];
        int i = ei[t];
        atomicAdd(&lcnt[u >> BSH], 1);
        atomicAdd(&lcnt[NBU + (i >> BSH)], 1);
    }
    __syncthreads();
    int* row = cntmat256 + (size_t)sub * NBUCK;
    for (int k = threadIdx.x; k < NBUCK; k += 256) row[k] = lcnt[k];
}

// ---------------- per-bucket scan over 256 subs -> localpfx + bucket total ----------------
__global__ void __launch_bounds__(256) bscan2_kernel(const int* __restrict__ cntmat256,
                                                     int* __restrict__ localpfx,
                                                     int* __restrict__ btot) {
    __shared__ int ws[4];
    int b = blockIdx.x;
    int t = threadIdx.x;
    int c = cntmat256[(size_t)t * NBUCK + b];
    int inc = c;
#pragma unroll
    for (int o = 1; o < 64; o <<= 1) {
        int x = __shfl_up(inc, o);
        if ((t & 63) >= o) inc += x;
    }
    if ((t & 63) == 63) ws[t >> 6] = inc;
    __syncthreads();
    int carry = 0;
#pragma unroll
    for (int w = 0; w < 4; w++) {
        if ((t >> 6) > w) carry += ws[w];
    }
    localpfx[(size_t)b * 256 + t] = carry + inc - c;   // exclusive prefix within bucket
    if (t == 255) btot[b] = carry + inc;               // bucket total
}

// ---------------- single-block exclusive scan over bucket totals -> bbase ----------------
__global__ void bscan_kernel(const int* __restrict__ btot, int* __restrict__ bbase) {
    __shared__ int s[256];
    int t = threadIdx.x;
    int v[10];                          // 256*10 = 2560 >= NBUCK
    int tot = 0;
#pragma unroll
    for (int k = 0; k < 10; k++) {
        int idx = t * 10 + k;
        v[k] = (idx < NBUCK) ? btot[idx] : 0;
        tot += v[k];
    }
    s[t] = tot;
    __syncthreads();
    for (int off = 1; off < 256; off <<= 1) {
        int x = (t >= off) ? s[t - off] : 0;
        __syncthreads();
        s[t] += x;
        __syncthreads();
    }
    int p = s[t] - tot;
#pragma unroll
    for (int k = 0; k < 10; k++) {
        int idx = t * 10 + k;
        if (idx < NBUCK) bbase[idx] = p;
        p += v[k];
    }
    if (t == 255) bbase[NBUCK] = TOTSLOTS;
}

// ---------------- per-(sub,cls) totals from cntmat256 ----------------
__global__ void __launch_bounds__(256) csum_kernel(const int* __restrict__ cntmat256,
                                                   int* __restrict__ csum) {
    int gid = blockIdx.x * 256 + threadIdx.x;   // 0..2047, sub-major: gid = sub*8+cls
    int sub = gid >> 3, cls = gid & 7;
    const int* row = cntmat256 + (size_t)sub * NBUCK;
    int s = 0;
    for (int q = 0; q < NQ; q++) {
        int b = q * 8 + cls;
        if (b < NBUCK) s += row[b];
    }
    csum[gid] = s;
}

// ---------------- exclusive scan over 2048 (sub,cls) totals -> cbase ----------------
__global__ void cbase_kernel(const int* __restrict__ csum, int* __restrict__ cbase) {
    __shared__ int s[256];
    int t = threadIdx.x;
    int v[8];
    int tot = 0;
#pragma unroll
    for (int k = 0; k < 8; k++) {
        v[k] = csum[t * 8 + k];
        tot += v[k];
    }
    s[t] = tot;
    __syncthreads();
    for (int off = 1; off < 256; off <<= 1) {
        int x = (t >= off) ? s[t - off] : 0;
        __syncthreads();
        s[t] += x;
        __syncthreads();
    }
    int p = s[t] - tot;
#pragma unroll
    for (int k = 0; k < 8; k++) {
        cbase[t * 8 + k] = p;
        p += v[k];
    }
    if (t == 255) cbase[2048] = TOTSLOTS;
}

// ---------------- phase A: 1x sweep, compact edges into per-(sub,cls) regions ----------------
__global__ void __launch_bounds__(256) cscatA_kernel(const int* __restrict__ eu,
                                                     const int* __restrict__ ei,
                                                     const float* __restrict__ vui,
                                                     const float* __restrict__ viu,
                                                     const int* __restrict__ cbase,
                                                     unsigned int* __restrict__ compact4,
                                                     unsigned short* __restrict__ compactA) {
    __shared__ int lbase8[8];
    __shared__ int lcnt8[8];
    int sub = blockIdx.x;
    if (threadIdx.x < 8) {
        lbase8[threadIdx.x] = cbase[sub * 8 + (int)threadIdx.x];
        lcnt8[threadIdx.x] = 0;
    }
    __syncthreads();
    for (int t = sub * 256 + (int)threadIdx.x; t < NEDGE; t += SUBS * 256) {
        int u = eu[t];
        int i = ei[t];
        float va = vui[t];
        float vb = viu[t];
        int bu = u >> BSH;
        int cls = bu & 7;
        int r = atomicAdd(&lcnt8[cls], 1);
        int pos = lbase8[cls] + r;
        compact4[pos] = ((unsigned int)i << 15) | ((unsigned int)f2b(va) & 0x7FFFu);
        compactA[pos] = (unsigned short)((((unsigned int)(bu >> 3)) << 6) | (unsigned int)(u & 63));
        int bid = NBU + (i >> BSH);
        int cls2 = bid & 7;
        int r2 = atomicAdd(&lcnt8[cls2], 1);
        int pos2 = lbase8[cls2] + r2;
        compact4[pos2] = ((unsigned int)u << 15) | ((unsigned int)f2b(vb) & 0x7FFFu);
        compactA[pos2] = (unsigned short)((((unsigned int)(bid >> 3)) << 6) | (unsigned int)(i & 63));
    }
}

// ---------------- phase B: per-(cls,sub) region -> bucket-ordered staging ----------------
__global__ void __launch_bounds__(256) scatterC_kernel(const unsigned int* __restrict__ compact4,
                                                       const unsigned short* __restrict__ compactA,
                                                       const int* __restrict__ cntmat256,
                                                       const int* __restrict__ localpfx,
                                                       const int* __restrict__ bbase,
                                                       const int* __restrict__ cbase,
                                                       unsigned int* __restrict__ staging4,
                                                       unsigned char* __restrict__ staging_off) {
    __shared__ int lofs[NQ + 1];
    __shared__ int lbase[NQ];
    __shared__ int lrank[NQ];
    __shared__ unsigned int lbuf4[BUFSZ];       // 16 KB
    __shared__ unsigned char lbufo[BUFSZ];      // 4 KB
    int cls = blockIdx.x & 7;
    int sub = blockIdx.x >> 3;
    for (int k = threadIdx.x; k < NQ; k += 256) {
        int b = k * 8 + cls;
        if (b < NBUCK) {
            lbase[k] = bbase[b] + localpfx[(size_t)b * 256 + sub];
            lofs[k + 1] = cntmat256[(size_t)sub * NBUCK + b];
        } else {
            lbase[k] = 0;
            lofs[k + 1] = 0;
        }
        lrank[k] = 0;
    }
    if (threadIdx.x == 0) lofs[0] = 0;
    __syncthreads();
    if (threadIdx.x < 64) {
        int carry = 0;
        for (int c = 0; c < 5; c++) {
            int idx = c * 64 + (int)threadIdx.x + 1;
            int v = (idx <= NQ) ? lofs[idx] : 0;
            int inc = v;
#pragma unroll
            for (int o = 1; o < 64; o <<= 1) {
                int x = __shfl_up(inc, o);
                if ((int)threadIdx.x >= o) inc += x;
            }
            if (idx <= NQ) lofs[idx] = carry + inc;
            carry += __shfl(inc, 63);
        }
    }
    __syncthreads();
    int total = lofs[NQ];
    int rbeg = cbase[sub * 8 + cls], rend = cbase[sub * 8 + cls + 1];
    for (int e = rbeg + (int)threadIdx.x; e < rend; e += 256) {
        unsigned int pay = compact4[e];
        unsigned int a = compactA[e];
        int q = (int)(a >> 6);
        unsigned char off = (unsigned char)(a & 63u);
        int r = atomicAdd(&lrank[q], 1);
        int pos = lofs[q] + r;
        if (pos < BUFSZ) { lbuf4[pos] = pay; lbufo[pos] = off; }
        else { staging4[lbase[q] + r] = pay; staging_off[lbase[q] + r] = off; }
    }
    __syncthreads();
    int fl = min(total, BUFSZ);
    for (int t = threadIdx.x; t < fl; t += 256) {
        int lo = 0, hi = NQ;
        while (hi - lo > 1) {
            int mid = (lo + hi) >> 1;
            if (lofs[mid] <= t) lo = mid; else hi = mid;
        }
        int g = lbase[lo] + (t - lofs[lo]);
        staging4[g] = lbuf4[t];
        staging_off[g] = lbufo[t];
    }
}

// ---------------- phase C: row counts -> rowptr -> row-ordered csr (direct copy) ----------------
__global__ void __launch_bounds__(256) rsort_kernel(const int* __restrict__ bbase,
                                                    const unsigned int* __restrict__ staging4,
                                                    const unsigned char* __restrict__ staging_off,
                                                    unsigned int* __restrict__ csr4,
                                                    int* __restrict__ rowptr) {
    __shared__ int fillr[64];
    __shared__ int rp[64];
    int b = blockIdx.x;
    int gRowBase, rows;
    if (b < NBU) {
        gRowBase = b << BSH;
        rows = min(64, U_NUM - gRowBase);
    } else {
        int rb = (b - NBU) << BSH;
        gRowBase = U_NUM + rb;
        rows = min(64, I_NUM - rb);
    }
    if (threadIdx.x < 64) fillr[threadIdx.x] = 0;
    __syncthreads();
    int beg = bbase[b], end = bbase[b + 1];
    for (int e = beg + (int)threadIdx.x; e < end; e += 256) {
        atomicAdd(&fillr[staging_off[e]], 1);
    }
    __syncthreads();
    if (threadIdx.x < 64) {
        int c = fillr[threadIdx.x];
        int inc = c;
#pragma unroll
        for (int o = 1; o < 64; o <<= 1) {
            int x = __shfl_up(inc, o);
            if ((int)threadIdx.x >= o) inc += x;
        }
        int excl = beg + inc - c;
        rp[threadIdx.x] = excl;
        if ((int)threadIdx.x < rows) rowptr[gRowBase + threadIdx.x] = excl;
        fillr[threadIdx.x] = 0;
    }
    if (b == 0 && threadIdx.x == 64) rowptr[NROWS] = TOTSLOTS;
    __syncthreads();
    for (int e = beg + (int)threadIdx.x; e < end; e += 256) {
        int off = staging_off[e];
        int dst = rp[off] + atomicAdd(&fillr[off], 1);
        csr4[dst] = staging4[e];
    }
}

// ---------------- propagation: quarter-wave per edge, uint2 (4 bf16 dims) per lane ----------------
// 16 lanes cover a 64-dim row at 8B/lane; the wave's 4 slot-groups process edges
// e+0..e+3 concurrently. Slot partial sums merged by shfl_xor(16)+(32); slot 0 writes.
// Halves VALU issues per edge vs R18's 4B/lane (VALUBusy was 56% = still issue-heavy).
__global__ void __launch_bounds__(256) agg_kernel(
        const unsigned short* __restrict__ uprev, const unsigned short* __restrict__ iprev,
        unsigned short* __restrict__ unext, unsigned short* __restrict__ inext,
        const float* __restrict__ di, const float* __restrict__ dj,
        const int* __restrict__ rowptr, const unsigned int* __restrict__ csr4) {
    int wid = (blockIdx.x * 256 + threadIdx.x) >> 6;
    int lane = threadIdx.x & 63;
    if (wid >= NROWS) return;
    int slot = lane >> 4;                          // edge slot 0..3
    unsigned int dq = (unsigned int)(lane & 15);   // dim-quad index
    const uint2* selfU;
    const uint2* srcU;
    uint2* dstU;
    float dscale;
    unsigned int r32;
    if (wid < U_NUM) {
        r32 = (unsigned int)wid;
        selfU = (const uint2*)uprev;
        srcU  = (const uint2*)iprev;
        dstU  = (uint2*)unext;
        dscale = di[wid];
    } else {
        r32 = (unsigned int)(wid - U_NUM);
        selfU = (const uint2*)iprev;
        srcU  = (const uint2*)uprev;
        dstU  = (uint2*)inext;
        dscale = dj[wid - U_NUM];
    }
    int beg = rowptr[wid], end = rowptr[wid + 1];
    unsigned int selfIdx = (r32 << 4) | dq;
    float acc0, acc1, acc2, acc3;
    {
        uint2 s = selfU[selfIdx];
        bool first = (slot == 0);
        acc0 = first ? b2f((unsigned short)(s.x & 0xFFFFu)) * dscale : 0.0f;
        acc1 = first ? b2f((unsigned short)(s.x >> 16)) * dscale : 0.0f;
        acc2 = first ? b2f((unsigned short)(s.y & 0xFFFFu)) * dscale : 0.0f;
        acc3 = first ? b2f((unsigned short)(s.y >> 16)) * dscale : 0.0f;
    }
    int e = beg;
    for (; e + 8 <= end; e += 8) {
        unsigned int pk[2];
        uint2 g[2];
        pk[0] = csr4[e + slot];
        pk[1] = csr4[e + 4 + slot];
        g[0] = srcU[((pk[0] >> 15) << 4) | dq];
        g[1] = srcU[((pk[1] >> 15) << 4) | dq];
#pragma unroll
        for (int k = 0; k < 2; k++) {
            float w = b2f((unsigned short)(pk[k] & 0x7FFFu));
            acc0 = fmaf(w, b2f((unsigned short)(g[k].x & 0xFFFFu)), acc0);
            acc1 = fmaf(w, b2f((unsigned short)(g[k].x >> 16)), acc1);
            acc2 = fmaf(w, b2f((unsigned short)(g[k].y & 0xFFFFu)), acc2);
            acc3 = fmaf(w, b2f((unsigned short)(g[k].y >> 16)), acc3);
        }
    }
    for (; e < end; e += 4) {
        int idx = e + slot;
        if (idx < end) {
            unsigned int pk = csr4[idx];
            uint2 g = srcU[((pk >> 15) << 4) | dq];
            float w = b2f((unsigned short)(pk & 0x7FFFu));
            acc0 = fmaf(w, b2f((unsigned short)(g.x & 0xFFFFu)), acc0);
            acc1 = fmaf(w, b2f((unsigned short)(g.x >> 16)), acc1);
            acc2 = fmaf(w, b2f((unsigned short)(g.y & 0xFFFFu)), acc2);
            acc3 = fmaf(w, b2f((unsigned short)(g.y >> 16)), acc3);
        }
    }
    acc0 += __shfl_xor(acc0, 16); acc0 += __shfl_xor(acc0, 32);
    acc1 += __shfl_xor(acc1, 16); acc1 += __shfl_xor(acc1, 32);
    acc2 += __shfl_xor(acc2, 16); acc2 += __shfl_xor(acc2, 32);
    acc3 += __shfl_xor(acc3, 16); acc3 += __shfl_xor(acc3, 32);
    if (slot == 0) {
        uint2 o;
        o.x = ((unsigned int)f2b(acc1) << 16) | (unsigned int)f2b(acc0);
        o.y = ((unsigned int)f2b(acc3) << 16) | (unsigned int)f2b(acc2);
        dstU[selfIdx] = o;
    }
}

// ---------------- BPR head ----------------
__global__ void __launch_bounds__(256) batch_kernel(
        const float* __restrict__ u0f, const float* __restrict__ i0f,
        const unsigned short* __restrict__ u1, const unsigned short* __restrict__ u2,
        const unsigned short* __restrict__ u3,
        const unsigned short* __restrict__ i1, const unsigned short* __restrict__ i2,
        const unsigned short* __restrict__ i3,
        const int* __restrict__ user, const int* __restrict__ ita, const int* __restrict__ itb,
        float* __restrict__ out, float* __restrict__ ls, float* __restrict__ l2a) {
    int wid = (blockIdx.x * 256 + threadIdx.x) >> 6;
    int lane = threadIdx.x & 63;
    if (wid >= BATCH) return;
    size_t uo = (size_t)user[wid] * FCT + lane;
    size_t ao = (size_t)ita[wid] * FCT + lane;
    size_t bo = (size_t)itb[wid] * FCT + lane;

    float pi, pj, l2;
    {
        float ue = u0f[uo], ie = i0f[ao], je = i0f[bo];
        pi = ue * ie; pj = ue * je; l2 = ue * ue + ie * ie + je * je;
    }
    const unsigned short* Ut[3] = {u1, u2, u3};
    const unsigned short* It[3] = {i1, i2, i3};
#pragma unroll
    for (int l = 0; l < 3; l++) {
        float ue = b2f(Ut[l][uo]), ie = b2f(It[l][ao]), je = b2f(It[l][bo]);
        pi += ue * ie;
        pj += ue * je;
        l2 += ue * ue + ie * ie + je * je;
    }
#pragma unroll
    for (int off = 32; off; off >>= 1) {
        pi += __shfl_xor(pi, off);
        pj += __shfl_xor(pj, off);
        l2 += __shfl_xor(l2, off);
    }
    if (lane == 0) {
        out[wid] = pi;
        out[BATCH + wid] = pj;
        float x = pi - pj;
        ls[wid] = fminf(x, 0.0f) - log1pf(expf(-fabsf(x)));
        l2a[wid] = 0.01f * l2;
    }
}

__global__ void final_kernel(const float* __restrict__ ls, const float* __restrict__ l2a,
                             float* __restrict__ out) {
    __shared__ float s1[256], s2[256];
    int t = threadIdx.x;
    float a = 0.f, b = 0.f;
    for (int i = t; i < BATCH; i += 256) {
        a += ls[i];
        b += l2a[i];
    }
    s1[t] = a;
    s2[t] = b;
    __syncthreads();
    for (int off = 128; off; off >>= 1) {
        if (t < off) {
            s1[t] += s1[t + off];
            s2[t] += s2[t + off];
        }
        __syncthreads();
    }
    if (t == 0) {
        float loss2 = -s1[0] / (float)BATCH;
        float l2m = s2[0] / (float)BATCH;
        out[2 * BATCH] = loss2 + l2m;
        out[2 * BATCH + 1] = loss2;
    }
}

// ---------------- launch ----------------
extern "C" void kernel_launch(void* const* d_in, const int* in_sizes, int n_in,
                              void* d_out, int out_size, void* d_ws, size_t ws_size,
                              hipStream_t stream) {
    const float* u0f = (const float*)d_in[0];
    const float* i0f = (const float*)d_in[1];
    const float* di  = (const float*)d_in[2];
    const float* dj  = (const float*)d_in[3];
    const float* vui = (const float*)d_in[4];
    const float* viu = (const float*)d_in[5];
    const int*   eu  = (const int*)d_in[6];
    const int*   ei  = (const int*)d_in[7];
    const int*   usr = (const int*)d_in[8];
    const int*   ita = (const int*)d_in[9];
    const int*   itb = (const int*)d_in[10];
    float* out = (float*)d_out;

    char* p = (char*)d_ws;
    auto alloc = [&](size_t bytes) -> char* {
        char* r = p;
        p += (bytes + 255) & ~(size_t)255;
        return r;
    };
    unsigned short* u0b = (unsigned short*)alloc((size_t)U_NUM * FCT * 2);
    unsigned short* u1b = (unsigned short*)alloc((size_t)U_NUM * FCT * 2);
    unsigned short* i0b = (unsigned short*)alloc((size_t)I_NUM * FCT * 2);
    unsigned short* i1b = (unsigned short*)alloc((size_t)I_NUM * FCT * 2);
    unsigned int* compact4   = (unsigned int*)alloc((size_t)TOTSLOTS * 4);    // 25.6 MB
    unsigned short* compactA = (unsigned short*)alloc((size_t)TOTSLOTS * 2);  // 12.8 MB
    unsigned int* staging4    = (unsigned int*)alloc((size_t)TOTSLOTS * 4);   // 25.6 MB
    unsigned char* staging_off = (unsigned char*)alloc((size_t)TOTSLOTS);     // 6.4 MB
    int* rowptr    = (int*)alloc((size_t)(NROWS + 1) * 4);
    int* cntmat256 = (int*)alloc((size_t)SUBS * NBUCK * 4);            // 2.4 MB
    int* localpfx  = (int*)alloc((size_t)NBUCK * SUBS * 4);            // 2.4 MB
    int* btot      = (int*)alloc((size_t)NBUCK * 4);
    int* bbase     = (int*)alloc((size_t)(NBUCK + 1) * 4);
    int* csum      = (int*)alloc((size_t)2048 * 4);
    int* cbase     = (int*)alloc((size_t)2049 * 4);
    float* ls      = (float*)alloc((size_t)BATCH * 4);
    float* l2a     = (float*)alloc((size_t)BATCH * 4);
    // overlays (disjoint lifetimes):
    //   csr4 <- compact4 ; i3b <- compactA ; u2b,u3b <- staging4 ; i2b <- staging_off
    unsigned int* csr4 = compact4;
    unsigned short* i3b = compactA;
    unsigned short* u2b = (unsigned short*)staging4;
    unsigned short* u3b = u2b + (size_t)U_NUM * FCT;
    unsigned short* i2b = (unsigned short*)staging_off;

    conv_kernel<<<(U_NUM * FCT / 4 + 255) / 256, 256, 0, stream>>>(u0f, u0b, U_NUM * FCT / 4);
    conv_kernel<<<(I_NUM * FCT / 4 + 255) / 256, 256, 0, stream>>>(i0f, i0b, I_NUM * FCT / 4);

    count256_kernel<<<SUBS, 256, 0, stream>>>(eu, ei, cntmat256);
    bscan2_kernel<<<NBUCK, 256, 0, stream>>>(cntmat256, localpfx, btot);
    bscan_kernel<<<1, 256, 0, stream>>>(btot, bbase);
    csum_kernel<<<8, 256, 0, stream>>>(cntmat256, csum);
    cbase_kernel<<<1, 256, 0, stream>>>(csum, cbase);

    cscatA_kernel<<<SUBS, 256, 0, stream>>>(eu, ei, vui, viu, cbase, compact4, compactA);
    scatterC_kernel<<<SUBS * 8, 256, 0, stream>>>(compact4, compactA, cntmat256, localpfx,
                                                  bbase, cbase, staging4, staging_off);
    rsort_kernel<<<NBUCK, 256, 0, stream>>>(bbase, staging4, staging_off, csr4, rowptr);

    int aggGrid = (NROWS * 64) / 256 + 1;
    agg_kernel<<<aggGrid, 256, 0, stream>>>(u0b, i0b, u1b, i1b, di, dj, rowptr, csr4);
    agg_kernel<<<aggGrid, 256, 0, stream>>>(u1b, i1b, u2b, i2b, di, dj, rowptr, csr4);
    agg_kernel<<<aggGrid, 256, 0, stream>>>(u2b, i2b, u3b, i3b, di, dj, rowptr, csr4);

    batch_kernel<<<(BATCH * 64) / 256, 256, 0, stream>>>(u0f, i0f, u1b, u2b, u3b,
                                                         i1b, i2b, i3b,
                                                         usr, ita, itb, out, ls, l2a);
    final_kernel<<<1, 256, 0, stream>>>(ls, l2a, out);
}

// Round 20
// 462.616 us; speedup vs baseline: 1.3066x; 1.1427x over previous
//
#include <hip/hip_runtime.h>

#define U_NUM   100000
#define I_NUM   50000
#define FCT     64
#define NEDGE   3200000
#define BATCH   16384
#define NROWS   (U_NUM + I_NUM)      // 150000
#define TOTSLOTS (2 * NEDGE)         // 6400000

#define BSH 6                        // 64 rows per bucket
#define NBU 1563                     // ceil(100000/64)
#define NBI 782                      // ceil(50000/64)
#define NBUCK (NBU + NBI)            // 2345
#define NQ   294                     // ceil(NBUCK/8) buckets per class
#define SUBS 256                     // slices
#define BUFSZ 4096                   // LDS payload slots (expected fill 3125)

__device__ __forceinline__ unsigned short f2b(float f) {
    unsigned int x = __float_as_uint(f);
    unsigned int r = (x + 0x7FFFu + ((x >> 16) & 1u)) >> 16;   // RNE
    return (unsigned short)r;
}
__device__ __forceinline__ float b2f(unsigned short u) {
    return __uint_as_float(((unsigned int)u) << 16);
}

// ---------------- fp32 -> bf16 table conversion ----------------
__global__ void conv_kernel(const float* __restrict__ in, unsigned short* __restrict__ out, int n4) {
    int t = blockIdx.x * blockDim.x + threadIdx.x;
    if (t >= n4) return;
    float4 v = *reinterpret_cast<const float4*>(in + (size_t)t * 4);
    ushort4 o;
    o.x = f2b(v.x); o.y = f2b(v.y); o.z = f2b(v.z); o.w = f2b(v.w);
    *reinterpret_cast<ushort4*>(out + (size_t)t * 4) = o;
}

// ---------------- single-sweep per-(sub,bucket) count ----------------
__global__ void __launch_bounds__(256) count256_kernel(const int* __restrict__ eu,
                                                       const int* __restrict__ ei,
                                                       int* __restrict__ cntmat256) {
    __shared__ int lcnt[NBUCK];
    for (int k = threadIdx.x; k < NBUCK; k += 256) lcnt[k] = 0;
    __syncthreads();
    int sub = blockIdx.x;
    for (int t = sub * 256 + (int)threadIdx.x; t < NEDGE; t += SUBS * 256) {
        int u = eu[t];
        int i = ei[t];
        atomicAdd(&lcnt[u >> BSH], 1);
        atomicAdd(&lcnt[NBU + (i >> BSH)], 1);
    }
    __syncthreads();
    int* row = cntmat256 + (size_t)sub * NBUCK;
    for (int k = threadIdx.x; k < NBUCK; k += 256) row[k] = lcnt[k];
}

// ---------------- per-bucket scan over 256 subs -> localpfx + bucket total ----------------
__global__ void __launch_bounds__(256) bscan2_kernel(const int* __restrict__ cntmat256,
                                                     int* __restrict__ localpfx,
                                                     int* __restrict__ btot) {
    __shared__ int ws[4];
    int b = blockIdx.x;
    int t = threadIdx.x;
    int c = cntmat256[(size_t)t * NBUCK + b];
    int inc = c;
#pragma unroll
    for (int o = 1; o < 64; o <<= 1) {
        int x = __shfl_up(inc, o);
        if ((t & 63) >= o) inc += x;
    }
    if ((t & 63) == 63) ws[t >> 6] = inc;
    __syncthreads();
    int carry = 0;
#pragma unroll
    for (int w = 0; w < 4; w++) {
        if ((t >> 6) > w) carry += ws[w];
    }
    localpfx[(size_t)b * 256 + t] = carry + inc - c;   // exclusive prefix within bucket
    if (t == 255) btot[b] = carry + inc;               // bucket total
}

// ---------------- single-block exclusive scan over bucket totals -> bbase ----------------
__global__ void bscan_kernel(const int* __restrict__ btot, int* __restrict__ bbase) {
    __shared__ int s[256];
    int t = threadIdx.x;
    int v[10];                          // 256*10 = 2560 >= NBUCK
    int tot = 0;
#pragma unroll
    for (int k = 0; k < 10; k++) {
        int idx = t * 10 + k;
        v[k] = (idx < NBUCK) ? btot[idx] : 0;
        tot += v[k];
    }
    s[t] = tot;
    __syncthreads();
    for (int off = 1; off < 256; off <<= 1) {
        int x = (t >= off) ? s[t - off] : 0;
        __syncthreads();
        s[t] += x;
        __syncthreads();
    }
    int p = s[t] - tot;
#pragma unroll
    for (int k = 0; k < 10; k++) {
        int idx = t * 10 + k;
        if (idx < NBUCK) bbase[idx] = p;
        p += v[k];
    }
    if (t == 255) bbase[NBUCK] = TOTSLOTS;
}

// ---------------- per-(sub,cls) totals from cntmat256 ----------------
__global__ void __launch_bounds__(256) csum_kernel(const int* __restrict__ cntmat256,
                                                   int* __restrict__ csum) {
    int gid = blockIdx.x * 256 + threadIdx.x;   // 0..2047, sub-major: gid = sub*8+cls
    int sub = gid >> 3, cls = gid & 7;
    const int* row = cntmat256 + (size_t)sub * NBUCK;
    int s = 0;
    for (int q = 0; q < NQ; q++) {
        int b = q * 8 + cls;
        if (b < NBUCK) s += row[b];
    }
    csum[gid] = s;
}

// ---------------- exclusive scan over 2048 (sub,cls) totals -> cbase ----------------
__global__ void cbase_kernel(const int* __restrict__ csum, int* __restrict__ cbase) {
    __shared__ int s[256];
    int t = threadIdx.x;
    int v[8];
    int tot = 0;
#pragma unroll
    for (int k = 0; k < 8; k++) {
        v[k] = csum[t * 8 + k];
        tot += v[k];
    }
    s[t] = tot;
    __syncthreads();
    for (int off = 1; off < 256; off <<= 1) {
        int x = (t >= off) ? s[t - off] : 0;
        __syncthreads();
        s[t] += x;
        __syncthreads();
    }
    int p = s[t] - tot;
#pragma unroll
    for (int k = 0; k < 8; k++) {
        cbase[t * 8 + k] = p;
        p += v[k];
    }
    if (t == 255) cbase[2048] = TOTSLOTS;
}

// ---------------- phase A: 1x sweep, compact edges into per-(sub,cls) regions ----------------
__global__ void __launch_bounds__(256) cscatA_kernel(const int* __restrict__ eu,
                                                     const int* __restrict__ ei,
                                                     const float* __restrict__ vui,
                                                     const float* __restrict__ viu,
                                                     const int* __restrict__ cbase,
                                                     unsigned int* __restrict__ compact4,
                                                     unsigned short* __restrict__ compactA) {
    __shared__ int lbase8[8];
    __shared__ int lcnt8[8];
    int sub = blockIdx.x;
    if (threadIdx.x < 8) {
        lbase8[threadIdx.x] = cbase[sub * 8 + (int)threadIdx.x];
        lcnt8[threadIdx.x] = 0;
    }
    __syncthreads();
    for (int t = sub * 256 + (int)threadIdx.x; t < NEDGE; t += SUBS * 256) {
        int u = eu[t];
        int i = ei[t];
        float va = vui[t];
        float vb = viu[t];
        int bu = u >> BSH;
        int cls = bu & 7;
        int r = atomicAdd(&lcnt8[cls], 1);
        int pos = lbase8[cls] + r;
        compact4[pos] = ((unsigned int)i << 15) | ((unsigned int)f2b(va) & 0x7FFFu);
        compactA[pos] = (unsigned short)((((unsigned int)(bu >> 3)) << 6) | (unsigned int)(u & 63));
        int bid = NBU + (i >> BSH);
        int cls2 = bid & 7;
        int r2 = atomicAdd(&lcnt8[cls2], 1);
        int pos2 = lbase8[cls2] + r2;
        compact4[pos2] = ((unsigned int)u << 15) | ((unsigned int)f2b(vb) & 0x7FFFu);
        compactA[pos2] = (unsigned short)((((unsigned int)(bid >> 3)) << 6) | (unsigned int)(i & 63));
    }
}

// ---------------- phase B: per-(cls,sub) region -> bucket-ordered staging ----------------
__global__ void __launch_bounds__(256) scatterC_kernel(const unsigned int* __restrict__ compact4,
                                                       const unsigned short* __restrict__ compactA,
                                                       const int* __restrict__ cntmat256,
                                                       const int* __restrict__ localpfx,
                                                       const int* __restrict__ bbase,
                                                       const int* __restrict__ cbase,
                                                       unsigned int* __restrict__ staging4,
                                                       unsigned char* __restrict__ staging_off) {
    __shared__ int lofs[NQ + 1];
    __shared__ int lbase[NQ];
    __shared__ int lrank[NQ];
    __shared__ unsigned int lbuf4[BUFSZ];       // 16 KB
    __shared__ unsigned char lbufo[BUFSZ];      // 4 KB
    int cls = blockIdx.x & 7;
    int sub = blockIdx.x >> 3;
    for (int k = threadIdx.x; k < NQ; k += 256) {
        int b = k * 8 + cls;
        if (b < NBUCK) {
            lbase[k] = bbase[b] + localpfx[(size_t)b * 256 + sub];
            lofs[k + 1] = cntmat256[(size_t)sub * NBUCK + b];
        } else {
            lbase[k] = 0;
            lofs[k + 1] = 0;
        }
        lrank[k] = 0;
    }
    if (threadIdx.x == 0) lofs[0] = 0;
    __syncthreads();
    if (threadIdx.x < 64) {
        int carry = 0;
        for (int c = 0; c < 5; c++) {
            int idx = c * 64 + (int)threadIdx.x + 1;
            int v = (idx <= NQ) ? lofs[idx] : 0;
            int inc = v;
#pragma unroll
            for (int o = 1; o < 64; o <<= 1) {
                int x = __shfl_up(inc, o);
                if ((int)threadIdx.x >= o) inc += x;
            }
            if (idx <= NQ) lofs[idx] = carry + inc;
            carry += __shfl(inc, 63);
        }
    }
    __syncthreads();
    int total = lofs[NQ];
    int rbeg = cbase[sub * 8 + cls], rend = cbase[sub * 8 + cls + 1];
    for (int e = rbeg + (int)threadIdx.x; e < rend; e += 256) {
        unsigned int pay = compact4[e];
        unsigned int a = compactA[e];
        int q = (int)(a >> 6);
        unsigned char off = (unsigned char)(a & 63u);
        int r = atomicAdd(&lrank[q], 1);
        int pos = lofs[q] + r;
        if (pos < BUFSZ) { lbuf4[pos] = pay; lbufo[pos] = off; }
        else { staging4[lbase[q] + r] = pay; staging_off[lbase[q] + r] = off; }
    }
    __syncthreads();
    int fl = min(total, BUFSZ);
    for (int t = threadIdx.x; t < fl; t += 256) {
        int lo = 0, hi = NQ;
        while (hi - lo > 1) {
            int mid = (lo + hi) >> 1;
            if (lofs[mid] <= t) lo = mid; else hi = mid;
        }
        int g = lbase[lo] + (t - lofs[lo]);
        staging4[g] = lbuf4[t];
        staging_off[g] = lbufo[t];
    }
}

// ---------------- phase C: row counts -> rowptr -> row-ordered csr (direct copy) ----------------
__global__ void __launch_bounds__(256) rsort_kernel(const int* __restrict__ bbase,
                                                    const unsigned int* __restrict__ staging4,
                                                    const unsigned char* __restrict__ staging_off,
                                                    unsigned int* __restrict__ csr4,
                                                    int* __restrict__ rowptr) {
    __shared__ int fillr[64];
    __shared__ int rp[64];
    int b = blockIdx.x;
    int gRowBase, rows;
    if (b < NBU) {
        gRowBase = b << BSH;
        rows = min(64, U_NUM - gRowBase);
    } else {
        int rb = (b - NBU) << BSH;
        gRowBase = U_NUM + rb;
        rows = min(64, I_NUM - rb);
    }
    if (threadIdx.x < 64) fillr[threadIdx.x] = 0;
    __syncthreads();
    int beg = bbase[b], end = bbase[b + 1];
    for (int e = beg + (int)threadIdx.x; e < end; e += 256) {
        atomicAdd(&fillr[staging_off[e]], 1);
    }
    __syncthreads();
    if (threadIdx.x < 64) {
        int c = fillr[threadIdx.x];
        int inc = c;
#pragma unroll
        for (int o = 1; o < 64; o <<= 1) {
            int x = __shfl_up(inc, o);
            if ((int)threadIdx.x >= o) inc += x;
        }
        int excl = beg + inc - c;
        rp[threadIdx.x] = excl;
        if ((int)threadIdx.x < rows) rowptr[gRowBase + threadIdx.x] = excl;
        fillr[threadIdx.x] = 0;
    }
    if (b == 0 && threadIdx.x == 64) rowptr[NROWS] = TOTSLOTS;
    __syncthreads();
    for (int e = beg + (int)threadIdx.x; e < end; e += 256) {
        int off = staging_off[e];
        int dst = rp[off] + atomicAdd(&fillr[off], 1);
        csr4[dst] = staging4[e];
    }
}

// ---------------- propagation: eighth-wave per edge, uint4 (8 bf16 dims) per lane ----------------
// 8 lanes cover a 64-dim row at 16B/lane; the wave's 8 slot-groups process edges
// e+0..e+7 concurrently. Per-edge overhead amortizes over 8 slots (~2.4 wave-insts/edge,
// near the 2.0 dim-work floor). Slot sums merged by shfl_xor(8,16,32); slot 0 writes.
__global__ void __launch_bounds__(256) agg_kernel(
        const unsigned short* __restrict__ uprev, const unsigned short* __restrict__ iprev,
        unsigned short* __restrict__ unext, unsigned short* __restrict__ inext,
        const float* __restrict__ di, const float* __restrict__ dj,
        const int* __restrict__ rowptr, const unsigned int* __restrict__ csr4) {
    int wid = (blockIdx.x * 256 + threadIdx.x) >> 6;
    int lane = threadIdx.x & 63;
    if (wid >= NROWS) return;
    int slot = lane >> 3;                          // edge slot 0..7
    unsigned int dq = (unsigned int)(lane & 7);    // uint4 index within row
    const uint4* selfU;
    const uint4* srcU;
    uint4* dstU;
    float dscale;
    unsigned int r32;
    if (wid < U_NUM) {
        r32 = (unsigned int)wid;
        selfU = (const uint4*)uprev;
        srcU  = (const uint4*)iprev;
        dstU  = (uint4*)unext;
        dscale = di[wid];
    } else {
        r32 = (unsigned int)(wid - U_NUM);
        selfU = (const uint4*)iprev;
        srcU  = (const uint4*)uprev;
        dstU  = (uint4*)inext;
        dscale = dj[wid - U_NUM];
    }
    int beg = rowptr[wid], end = rowptr[wid + 1];
    unsigned int selfIdx = (r32 << 3) | dq;
    float acc[8];
    {
        uint4 s = selfU[selfIdx];
        bool first = (slot == 0);
        unsigned int sw[4] = {s.x, s.y, s.z, s.w};
#pragma unroll
        for (int d = 0; d < 4; d++) {
            acc[2 * d]     = first ? b2f((unsigned short)(sw[d] & 0xFFFFu)) * dscale : 0.0f;
            acc[2 * d + 1] = first ? b2f((unsigned short)(sw[d] >> 16)) * dscale : 0.0f;
        }
    }
    int e = beg;
    for (; e + 16 <= end; e += 16) {
        unsigned int pk0 = csr4[e + slot];
        unsigned int pk1 = csr4[e + 8 + slot];
        uint4 g0 = srcU[((pk0 >> 15) << 3) | dq];
        uint4 g1 = srcU[((pk1 >> 15) << 3) | dq];
        float w0 = b2f((unsigned short)(pk0 & 0x7FFFu));
        float w1 = b2f((unsigned short)(pk1 & 0x7FFFu));
        unsigned int gw0[4] = {g0.x, g0.y, g0.z, g0.w};
        unsigned int gw1[4] = {g1.x, g1.y, g1.z, g1.w};
#pragma unroll
        for (int d = 0; d < 4; d++) {
            acc[2 * d]     = fmaf(w0, b2f((unsigned short)(gw0[d] & 0xFFFFu)), acc[2 * d]);
            acc[2 * d + 1] = fmaf(w0, b2f((unsigned short)(gw0[d] >> 16)), acc[2 * d + 1]);
        }
#pragma unroll
        for (int d = 0; d < 4; d++) {
            acc[2 * d]     = fmaf(w1, b2f((unsigned short)(gw1[d] & 0xFFFFu)), acc[2 * d]);
            acc[2 * d + 1] = fmaf(w1, b2f((unsigned short)(gw1[d] >> 16)), acc[2 * d + 1]);
        }
    }
    for (; e < end; e += 8) {
        int idx = e + slot;
        if (idx < end) {
            unsigned int pk = csr4[idx];
            uint4 g = srcU[((pk >> 15) << 3) | dq];
            float w = b2f((unsigned short)(pk & 0x7FFFu));
            unsigned int gw[4] = {g.x, g.y, g.z, g.w};
#pragma unroll
            for (int d = 0; d < 4; d++) {
                acc[2 * d]     = fmaf(w, b2f((unsigned short)(gw[d] & 0xFFFFu)), acc[2 * d]);
                acc[2 * d + 1] = fmaf(w, b2f((unsigned short)(gw[d] >> 16)), acc[2 * d + 1]);
            }
        }
    }
#pragma unroll
    for (int d = 0; d < 8; d++) {
        acc[d] += __shfl_xor(acc[d], 8);
        acc[d] += __shfl_xor(acc[d], 16);
        acc[d] += __shfl_xor(acc[d], 32);
    }
    if (slot == 0) {
        uint4 o;
        o.x = ((unsigned int)f2b(acc[1]) << 16) | (unsigned int)f2b(acc[0]);
        o.y = ((unsigned int)f2b(acc[3]) << 16) | (unsigned int)f2b(acc[2]);
        o.z = ((unsigned int)f2b(acc[5]) << 16) | (unsigned int)f2b(acc[4]);
        o.w = ((unsigned int)f2b(acc[7]) << 16) | (unsigned int)f2b(acc[6]);
        dstU[selfIdx] = o;
    }
}

// ---------------- BPR head ----------------
__global__ void __launch_bounds__(256) batch_kernel(
        const float* __restrict__ u0f, const float* __restrict__ i0f,
        const unsigned short* __restrict__ u1, const unsigned short* __restrict__ u2,
        const unsigned short* __restrict__ u3,
        const unsigned short* __restrict__ i1, const unsigned short* __restrict__ i2,
        const unsigned short* __restrict__ i3,
        const int* __restrict__ user, const int* __restrict__ ita, const int* __restrict__ itb,
        float* __restrict__ out, float* __restrict__ ls, float* __restrict__ l2a) {
    int wid = (blockIdx.x * 256 + threadIdx.x) >> 6;
    int lane = threadIdx.x & 63;
    if (wid >= BATCH) return;
    size_t uo = (size_t)user[wid] * FCT + lane;
    size_t ao = (size_t)ita[wid] * FCT + lane;
    size_t bo = (size_t)itb[wid] * FCT + lane;

    float pi, pj, l2;
    {
        float ue = u0f[uo], ie = i0f[ao], je = i0f[bo];
        pi = ue * ie; pj = ue * je; l2 = ue * ue + ie * ie + je * je;
    }
    const unsigned short* Ut[3] = {u1, u2, u3};
    const unsigned short* It[3] = {i1, i2, i3};
#pragma unroll
    for (int l = 0; l < 3; l++) {
        float ue = b2f(Ut[l][uo]), ie = b2f(It[l][ao]), je = b2f(It[l][bo]);
        pi += ue * ie;
        pj += ue * je;
        l2 += ue * ue + ie * ie + je * je;
    }
#pragma unroll
    for (int off = 32; off; off >>= 1) {
        pi += __shfl_xor(pi, off);
        pj += __shfl_xor(pj, off);
        l2 += __shfl_xor(l2, off);
    }
    if (lane == 0) {
        out[wid] = pi;
        out[BATCH + wid] = pj;
        float x = pi - pj;
        ls[wid] = fminf(x, 0.0f) - log1pf(expf(-fabsf(x)));
        l2a[wid] = 0.01f * l2;
    }
}

__global__ void final_kernel(const float* __restrict__ ls, const float* __restrict__ l2a,
                             float* __restrict__ out) {
    __shared__ float s1[256], s2[256];
    int t = threadIdx.x;
    float a = 0.f, b = 0.f;
    for (int i = t; i < BATCH; i += 256) {
        a += ls[i];
        b += l2a[i];
    }
    s1[t] = a;
    s2[t] = b;
    __syncthreads();
    for (int off = 128; off; off >>= 1) {
        if (t < off) {
            s1[t] += s1[t + off];
            s2[t] += s2[t + off];
        }
        __syncthreads();
    }
    if (t == 0) {
        float loss2 = -s1[0] / (float)BATCH;
        float l2m = s2[0] / (float)BATCH;
        out[2 * BATCH] = loss2 + l2m;
        out[2 * BATCH + 1] = loss2;
    }
}

// ---------------- launch ----------------
extern "C" void kernel_launch(void* const* d_in, const int* in_sizes, int n_in,
                              void* d_out, int out_size, void* d_ws, size_t ws_size,
                              hipStream_t stream) {
    const float* u0f = (const float*)d_in[0];
    const float* i0f = (const float*)d_in[1];
    const float* di  = (const float*)d_in[2];
    const float* dj  = (const float*)d_in[3];
    const float* vui = (const float*)d_in[4];
    const float* viu = (const float*)d_in[5];
    const int*   eu  = (const int*)d_in[6];
    const int*   ei  = (const int*)d_in[7];
    const int*   usr = (const int*)d_in[8];
    const int*   ita = (const int*)d_in[9];
    const int*   itb = (const int*)d_in[10];
    float* out = (float*)d_out;

    char* p = (char*)d_ws;
    auto alloc = [&](size_t bytes) -> char* {
        char* r = p;
        p += (bytes + 255) & ~(size_t)255;
        return r;
    };
    unsigned short* u0b = (unsigned short*)alloc((size_t)U_NUM * FCT * 2);
    unsigned short* u1b = (unsigned short*)alloc((size_t)U_NUM * FCT * 2);
    unsigned short* i0b = (unsigned short*)alloc((size_t)I_NUM * FCT * 2);
    unsigned short* i1b = (unsigned short*)alloc((size_t)I_NUM * FCT * 2);
    unsigned int* compact4   = (unsigned int*)alloc((size_t)TOTSLOTS * 4);    // 25.6 MB
    unsigned short* compactA = (unsigned short*)alloc((size_t)TOTSLOTS * 2);  // 12.8 MB
    unsigned int* staging4    = (unsigned int*)alloc((size_t)TOTSLOTS * 4);   // 25.6 MB
    unsigned char* staging_off = (unsigned char*)alloc((size_t)TOTSLOTS);     // 6.4 MB
    int* rowptr    = (int*)alloc((size_t)(NROWS + 1) * 4);
    int* cntmat256 = (int*)alloc((size_t)SUBS * NBUCK * 4);            // 2.4 MB
    int* localpfx  = (int*)alloc((size_t)NBUCK * SUBS * 4);            // 2.4 MB
    int* btot      = (int*)alloc((size_t)NBUCK * 4);
    int* bbase     = (int*)alloc((size_t)(NBUCK + 1) * 4);
    int* csum      = (int*)alloc((size_t)2048 * 4);
    int* cbase     = (int*)alloc((size_t)2049 * 4);
    float* ls      = (float*)alloc((size_t)BATCH * 4);
    float* l2a     = (float*)alloc((size_t)BATCH * 4);
    // overlays (disjoint lifetimes):
    //   csr4 <- compact4 ; i3b <- compactA ; u2b,u3b <- staging4 ; i2b <- staging_off
    unsigned int* csr4 = compact4;
    unsigned short* i3b = compactA;
    unsigned short* u2b = (unsigned short*)staging4;
    unsigned short* u3b = u2b + (size_t)U_NUM * FCT;
    unsigned short* i2b = (unsigned short*)staging_off;

    conv_kernel<<<(U_NUM * FCT / 4 + 255) / 256, 256, 0, stream>>>(u0f, u0b, U_NUM * FCT / 4);
    conv_kernel<<<(I_NUM * FCT / 4 + 255) / 256, 256, 0, stream>>>(i0f, i0b, I_NUM * FCT / 4);

    count256_kernel<<<SUBS, 256, 0, stream>>>(eu, ei, cntmat256);
    bscan2_kernel<<<NBUCK, 256, 0, stream>>>(cntmat256, localpfx, btot);
    bscan_kernel<<<1, 256, 0, stream>>>(btot, bbase);
    csum_kernel<<<8, 256, 0, stream>>>(cntmat256, csum);
    cbase_kernel<<<1, 256, 0, stream>>>(csum, cbase);

    cscatA_kernel<<<SUBS, 256, 0, stream>>>(eu, ei, vui, viu, cbase, compact4, compactA);
    scatterC_kernel<<<SUBS * 8, 256, 0, stream>>>(compact4, compactA, cntmat256, localpfx,
                                                  bbase, cbase, staging4, staging_off);
    rsort_kernel<<<NBUCK, 256, 0, stream>>>(bbase, staging4, staging_off, csr4, rowptr);

    int aggGrid = (NROWS * 64) / 256 + 1;
    agg_kernel<<<aggGrid, 256, 0, stream>>>(u0b, i0b, u1b, i1b, di, dj, rowptr, csr4);
    agg_kernel<<<aggGrid, 256, 0, stream>>>(u1b, i1b, u2b, i2b, di, dj, rowptr, csr4);
    agg_kernel<<<aggGrid, 256, 0, stream>>>(u2b, i2b, u3b, i3b, di, dj, rowptr, csr4);

    batch_kernel<<<(BATCH * 64) / 256, 256, 0, stream>>>(u0f, i0f, u1b, u2b, u3b,
                                                         i1b, i2b, i3b,
                                                         usr, ita, itb, out, ls, l2a);
    final_kernel<<<1, 256, 0, stream>>>(ls, l2a, out);
}

// Round 21
// 450.806 us; speedup vs baseline: 1.3408x; 1.0262x over previous
//
#include <hip/hip_runtime.h>

#define U_NUM   100000
#define I_NUM   50000
#define FCT     64
#define NEDGE   3200000
#define BATCH   16384
#define NROWS   (U_NUM + I_NUM)      // 150000
#define TOTSLOTS (2 * NEDGE)         // 6400000

#define BSH 6                        // 64 rows per bucket
#define NBU 1563                     // ceil(100000/64)
#define NBI 782                      // ceil(50000/64)
#define NBUCK (NBU + NBI)            // 2345
#define NQ   294                     // ceil(NBUCK/8) buckets per class
#define SUBS 256                     // slices
#define BUFSZ 4096                   // LDS payload slots (expected fill 3125)

__device__ __forceinline__ unsigned short f2b(float f) {
    unsigned int x = __float_as_uint(f);
    unsigned int r = (x + 0x7FFFu + ((x >> 16) & 1u)) >> 16;   // RNE
    return (unsigned short)r;
}
__device__ __forceinline__ float b2f(unsigned short u) {
    return __uint_as_float(((unsigned int)u) << 16);
}

// ---------------- fp32 -> bf16 table conversion ----------------
__global__ void conv_kernel(const float* __restrict__ in, unsigned short* __restrict__ out, int n4) {
    int t = blockIdx.x * blockDim.x + threadIdx.x;
    if (t >= n4) return;
    float4 v = *reinterpret_cast<const float4*>(in + (size_t)t * 4);
    ushort4 o;
    o.x = f2b(v.x); o.y = f2b(v.y); o.z = f2b(v.z); o.w = f2b(v.w);
    *reinterpret_cast<ushort4*>(out + (size_t)t * 4) = o;
}

// ---------------- single-sweep per-(sub,bucket) count ----------------
__global__ void __launch_bounds__(256) count256_kernel(const int* __restrict__ eu,
                                                       const int* __restrict__ ei,
                                                       int* __restrict__ cntmat256) {
    __shared__ int lcnt[NBUCK];
    for (int k = threadIdx.x; k < NBUCK; k += 256) lcnt[k] = 0;
    __syncthreads();
    int sub = blockIdx.x;
    for (int t = sub * 256 + (int)threadIdx.x; t < NEDGE; t += SUBS * 256) {
        int u = eu[t];
        int i = ei[t];
        atomicAdd(&lcnt[u >> BSH], 1);
        atomicAdd(&lcnt[NBU + (i >> BSH)], 1);
    }
    __syncthreads();
    int* row = cntmat256 + (size_t)sub * NBUCK;
    for (int k = threadIdx.x; k < NBUCK; k += 256) row[k] = lcnt[k];
}

// ---------------- per-bucket scan over 256 subs -> localpfx + bucket total ----------------
__global__ void __launch_bounds__(256) bscan2_kernel(const int* __restrict__ cntmat256,
                                                     int* __restrict__ localpfx,
                                                     int* __restrict__ btot) {
    __shared__ int ws[4];
    int b = blockIdx.x;
    int t = threadIdx.x;
    int c = cntmat256[(size_t)t * NBUCK + b];
    int inc = c;
#pragma unroll
    for (int o = 1; o < 64; o <<= 1) {
        int x = __shfl_up(inc, o);
        if ((t & 63) >= o) inc += x;
    }
    if ((t & 63) == 63) ws[t >> 6] = inc;
    __syncthreads();
    int carry = 0;
#pragma unroll
    for (int w = 0; w < 4; w++) {
        if ((t >> 6) > w) carry += ws[w];
    }
    localpfx[(size_t)b * 256 + t] = carry + inc - c;   // exclusive prefix within bucket
    if (t == 255) btot[b] = carry + inc;               // bucket total
}

// ---------------- single-block exclusive scan over bucket totals -> bbase ----------------
__global__ void bscan_kernel(const int* __restrict__ btot, int* __restrict__ bbase) {
    __shared__ int s[256];
    int t = threadIdx.x;
    int v[10];                          // 256*10 = 2560 >= NBUCK
    int tot = 0;
#pragma unroll
    for (int k = 0; k < 10; k++) {
        int idx = t * 10 + k;
        v[k] = (idx < NBUCK) ? btot[idx] : 0;
        tot += v[k];
    }
    s[t] = tot;
    __syncthreads();
    for (int off = 1; off < 256; off <<= 1) {
        int x = (t >= off) ? s[t - off] : 0;
        __syncthreads();
        s[t] += x;
        __syncthreads();
    }
    int p = s[t] - tot;
#pragma unroll
    for (int k = 0; k < 10; k++) {
        int idx = t * 10 + k;
        if (idx < NBUCK) bbase[idx] = p;
        p += v[k];
    }
    if (t == 255) bbase[NBUCK] = TOTSLOTS;
}

// ---------------- per-(sub,cls) totals from cntmat256 ----------------
__global__ void __launch_bounds__(256) csum_kernel(const int* __restrict__ cntmat256,
                                                   int* __restrict__ csum) {
    int gid = blockIdx.x * 256 + threadIdx.x;   // 0..2047, sub-major: gid = sub*8+cls
    int sub = gid >> 3, cls = gid & 7;
    const int* row = cntmat256 + (size_t)sub * NBUCK;
    int s = 0;
    for (int q = 0; q < NQ; q++) {
        int b = q * 8 + cls;
        if (b < NBUCK) s += row[b];
    }
    csum[gid] = s;
}

// ---------------- exclusive scan over 2048 (sub,cls) totals -> cbase ----------------
__global__ void cbase_kernel(const int* __restrict__ csum, int* __restrict__ cbase) {
    __shared__ int s[256];
    int t = threadIdx.x;
    int v[8];
    int tot = 0;
#pragma unroll
    for (int k = 0; k < 8; k++) {
        v[k] = csum[t * 8 + k];
        tot += v[k];
    }
    s[t] = tot;
    __syncthreads();
    for (int off = 1; off < 256; off <<= 1) {
        int x = (t >= off) ? s[t - off] : 0;
        __syncthreads();
        s[t] += x;
        __syncthreads();
    }
    int p = s[t] - tot;
#pragma unroll
    for (int k = 0; k < 8; k++) {
        cbase[t * 8 + k] = p;
        p += v[k];
    }
    if (t == 255) cbase[2048] = TOTSLOTS;
}

// ---------------- phase A: 1x sweep, compact edges into per-(sub,cls) regions ----------------
__global__ void __launch_bounds__(256) cscatA_kernel(const int* __restrict__ eu,
                                                     const int* __restrict__ ei,
                                                     const float* __restrict__ vui,
                                                     const float* __restrict__ viu,
                                                     const int* __restrict__ cbase,
                                                     unsigned int* __restrict__ compact4,
                                                     unsigned short* __restrict__ compactA) {
    __shared__ int lbase8[8];
    __shared__ int lcnt8[8];
    int sub = blockIdx.x;
    if (threadIdx.x < 8) {
        lbase8[threadIdx.x] = cbase[sub * 8 + (int)threadIdx.x];
        lcnt8[threadIdx.x] = 0;
    }
    __syncthreads();
    for (int t = sub * 256 + (int)threadIdx.x; t < NEDGE; t += SUBS * 256) {
        int u = eu[t];
        int i = ei[t];
        float va = vui[t];
        float vb = viu[t];
        int bu = u >> BSH;
        int cls = bu & 7;
        int r = atomicAdd(&lcnt8[cls], 1);
        int pos = lbase8[cls] + r;
        compact4[pos] = ((unsigned int)i << 15) | ((unsigned int)f2b(va) & 0x7FFFu);
        compactA[pos] = (unsigned short)((((unsigned int)(bu >> 3)) << 6) | (unsigned int)(u & 63));
        int bid = NBU + (i >> BSH);
        int cls2 = bid & 7;
        int r2 = atomicAdd(&lcnt8[cls2], 1);
        int pos2 = lbase8[cls2] + r2;
        compact4[pos2] = ((unsigned int)u << 15) | ((unsigned int)f2b(vb) & 0x7FFFu);
        compactA[pos2] = (unsigned short)((((unsigned int)(bid >> 3)) << 6) | (unsigned int)(i & 63));
    }
}

// ---------------- phase B: per-(cls,sub) region -> bucket-ordered staging ----------------
__global__ void __launch_bounds__(256) scatterC_kernel(const unsigned int* __restrict__ compact4,
                                                       const unsigned short* __restrict__ compactA,
                                                       const int* __restrict__ cntmat256,
                                                       const int* __restrict__ localpfx,
                                                       const int* __restrict__ bbase,
                                                       const int* __restrict__ cbase,
                                                       unsigned int* __restrict__ staging4,
                                                       unsigned char* __restrict__ staging_off) {
    __shared__ int lofs[NQ + 1];
    __shared__ int lbase[NQ];
    __shared__ int lrank[NQ];
    __shared__ unsigned int lbuf4[BUFSZ];       // 16 KB
    __shared__ unsigned char lbufo[BUFSZ];      // 4 KB
    int cls = blockIdx.x & 7;
    int sub = blockIdx.x >> 3;
    for (int k = threadIdx.x; k < NQ; k += 256) {
        int b = k * 8 + cls;
        if (b < NBUCK) {
            lbase[k] = bbase[b] + localpfx[(size_t)b * 256 + sub];
            lofs[k + 1] = cntmat256[(size_t)sub * NBUCK + b];
        } else {
            lbase[k] = 0;
            lofs[k + 1] = 0;
        }
        lrank[k] = 0;
    }
    if (threadIdx.x == 0) lofs[0] = 0;
    __syncthreads();
    if (threadIdx.x < 64) {
        int carry = 0;
        for (int c = 0; c < 5; c++) {
            int idx = c * 64 + (int)threadIdx.x + 1;
            int v = (idx <= NQ) ? lofs[idx] : 0;
            int inc = v;
#pragma unroll
            for (int o = 1; o < 64; o <<= 1) {
                int x = __shfl_up(inc, o);
                if ((int)threadIdx.x >= o) inc += x;
            }
            if (idx <= NQ) lofs[idx] = carry + inc;
            carry += __shfl(inc, 63);
        }
    }
    __syncthreads();
    int total = lofs[NQ];
    int rbeg = cbase[sub * 8 + cls], rend = cbase[sub * 8 + cls + 1];
    for (int e = rbeg + (int)threadIdx.x; e < rend; e += 256) {
        unsigned int pay = compact4[e];
        unsigned int a = compactA[e];
        int q = (int)(a >> 6);
        unsigned char off = (unsigned char)(a & 63u);
        int r = atomicAdd(&lrank[q], 1);
        int pos = lofs[q] + r;
        if (pos < BUFSZ) { lbuf4[pos] = pay; lbufo[pos] = off; }
        else { staging4[lbase[q] + r] = pay; staging_off[lbase[q] + r] = off; }
    }
    __syncthreads();
    int fl = min(total, BUFSZ);
    for (int t = threadIdx.x; t < fl; t += 256) {
        int lo = 0, hi = NQ;
        while (hi - lo > 1) {
            int mid = (lo + hi) >> 1;
            if (lofs[mid] <= t) lo = mid; else hi = mid;
        }
        int g = lbase[lo] + (t - lofs[lo]);
        staging4[g] = lbuf4[t];
        staging_off[g] = lbufo[t];
    }
}

// ---------------- phase C: row counts -> rowptr -> row-ordered csr (direct copy) ----------------
__global__ void __launch_bounds__(256) rsort_kernel(const int* __restrict__ bbase,
                                                    const unsigned int* __restrict__ staging4,
                                                    const unsigned char* __restrict__ staging_off,
                                                    unsigned int* __restrict__ csr4,
                                                    int* __restrict__ rowptr) {
    __shared__ int fillr[64];
    __shared__ int rp[64];
    int b = blockIdx.x;
    int gRowBase, rows;
    if (b < NBU) {
        gRowBase = b << BSH;
        rows = min(64, U_NUM - gRowBase);
    } else {
        int rb = (b - NBU) << BSH;
        gRowBase = U_NUM + rb;
        rows = min(64, I_NUM - rb);
    }
    if (threadIdx.x < 64) fillr[threadIdx.x] = 0;
    __syncthreads();
    int beg = bbase[b], end = bbase[b + 1];
    for (int e = beg + (int)threadIdx.x; e < end; e += 256) {
        atomicAdd(&fillr[staging_off[e]], 1);
    }
    __syncthreads();
    if (threadIdx.x < 64) {
        int c = fillr[threadIdx.x];
        int inc = c;
#pragma unroll
        for (int o = 1; o < 64; o <<= 1) {
            int x = __shfl_up(inc, o);
            if ((int)threadIdx.x >= o) inc += x;
        }
        int excl = beg + inc - c;
        rp[threadIdx.x] = excl;
        if ((int)threadIdx.x < rows) rowptr[gRowBase + threadIdx.x] = excl;
        fillr[threadIdx.x] = 0;
    }
    if (b == 0 && threadIdx.x == 64) rowptr[NROWS] = TOTSLOTS;
    __syncthreads();
    for (int e = beg + (int)threadIdx.x; e < end; e += 256) {
        int off = staging_off[e];
        int dst = rp[off] + atomicAdd(&fillr[off], 1);
        csr4[dst] = staging4[e];
    }
}

// ---------------- propagation: eighth-wave per edge, uint4 per lane, 4 gathers in flight ----------------
// 8 lanes/row, 8 edge slots/wave. Main loop = 32 edges/iter with pk[4]/g[4] issued
// up front (4 outstanding gathers hides L2/L3 latency; R20 showed 39% stall at depth 2).
// User rows (avg deg 32) ~1 main iter; item rows (avg 64) ~2. Tail: 16-wide step + 8-wide predicated.
__global__ void __launch_bounds__(256) agg_kernel(
        const unsigned short* __restrict__ uprev, const unsigned short* __restrict__ iprev,
        unsigned short* __restrict__ unext, unsigned short* __restrict__ inext,
        const float* __restrict__ di, const float* __restrict__ dj,
        const int* __restrict__ rowptr, const unsigned int* __restrict__ csr4) {
    int wid = (blockIdx.x * 256 + threadIdx.x) >> 6;
    int lane = threadIdx.x & 63;
    if (wid >= NROWS) return;
    int slot = lane >> 3;                          // edge slot 0..7
    unsigned int dq = (unsigned int)(lane & 7);    // uint4 index within row
    const uint4* selfU;
    const uint4* srcU;
    uint4* dstU;
    float dscale;
    unsigned int r32;
    if (wid < U_NUM) {
        r32 = (unsigned int)wid;
        selfU = (const uint4*)uprev;
        srcU  = (const uint4*)iprev;
        dstU  = (uint4*)unext;
        dscale = di[wid];
    } else {
        r32 = (unsigned int)(wid - U_NUM);
        selfU = (const uint4*)iprev;
        srcU  = (const uint4*)uprev;
        dstU  = (uint4*)inext;
        dscale = dj[wid - U_NUM];
    }
    int beg = rowptr[wid], end = rowptr[wid + 1];
    unsigned int selfIdx = (r32 << 3) | dq;
    float acc[8];
    {
        uint4 s = selfU[selfIdx];
        bool first = (slot == 0);
        unsigned int sw[4] = {s.x, s.y, s.z, s.w};
#pragma unroll
        for (int d = 0; d < 4; d++) {
            acc[2 * d]     = first ? b2f((unsigned short)(sw[d] & 0xFFFFu)) * dscale : 0.0f;
            acc[2 * d + 1] = first ? b2f((unsigned short)(sw[d] >> 16)) * dscale : 0.0f;
        }
    }
    int e = beg;
    // main: 32 edges per iteration, 4 gathers outstanding
    for (; e + 32 <= end; e += 32) {
        unsigned int pk[4];
        uint4 g[4];
#pragma unroll
        for (int k = 0; k < 4; k++) pk[k] = csr4[e + 8 * k + slot];
#pragma unroll
        for (int k = 0; k < 4; k++) g[k] = srcU[((pk[k] >> 15) << 3) | dq];
#pragma unroll
        for (int k = 0; k < 4; k++) {
            float w = b2f((unsigned short)(pk[k] & 0x7FFFu));
            unsigned int gw[4] = {g[k].x, g[k].y, g[k].z, g[k].w};
#pragma unroll
            for (int d = 0; d < 4; d++) {
                acc[2 * d]     = fmaf(w, b2f((unsigned short)(gw[d] & 0xFFFFu)), acc[2 * d]);
                acc[2 * d + 1] = fmaf(w, b2f((unsigned short)(gw[d] >> 16)), acc[2 * d + 1]);
            }
        }
    }
    // 16-wide step
    if (e + 16 <= end) {
        unsigned int pk[2];
        uint4 g[2];
#pragma unroll
        for (int k = 0; k < 2; k++) pk[k] = csr4[e + 8 * k + slot];
#pragma unroll
        for (int k = 0; k < 2; k++) g[k] = srcU[((pk[k] >> 15) << 3) | dq];
#pragma unroll
        for (int k = 0; k < 2; k++) {
            float w = b2f((unsigned short)(pk[k] & 0x7FFFu));
            unsigned int gw[4] = {g[k].x, g[k].y, g[k].z, g[k].w};
#pragma unroll
            for (int d = 0; d < 4; d++) {
                acc[2 * d]     = fmaf(w, b2f((unsigned short)(gw[d] & 0xFFFFu)), acc[2 * d]);
                acc[2 * d + 1] = fmaf(w, b2f((unsigned short)(gw[d] >> 16)), acc[2 * d + 1]);
            }
        }
        e += 16;
    }
    // tail: 8-wide predicated
    for (; e < end; e += 8) {
        int idx = e + slot;
        if (idx < end) {
            unsigned int pk = csr4[idx];
            uint4 g = srcU[((pk >> 15) << 3) | dq];
            float w = b2f((unsigned short)(pk & 0x7FFFu));
            unsigned int gw[4] = {g.x, g.y, g.z, g.w};
#pragma unroll
            for (int d = 0; d < 4; d++) {
                acc[2 * d]     = fmaf(w, b2f((unsigned short)(gw[d] & 0xFFFFu)), acc[2 * d]);
                acc[2 * d + 1] = fmaf(w, b2f((unsigned short)(gw[d] >> 16)), acc[2 * d + 1]);
            }
        }
    }
#pragma unroll
    for (int d = 0; d < 8; d++) {
        acc[d] += __shfl_xor(acc[d], 8);
        acc[d] += __shfl_xor(acc[d], 16);
        acc[d] += __shfl_xor(acc[d], 32);
    }
    if (slot == 0) {
        uint4 o;
        o.x = ((unsigned int)f2b(acc[1]) << 16) | (unsigned int)f2b(acc[0]);
        o.y = ((unsigned int)f2b(acc[3]) << 16) | (unsigned int)f2b(acc[2]);
        o.z = ((unsigned int)f2b(acc[5]) << 16) | (unsigned int)f2b(acc[4]);
        o.w = ((unsigned int)f2b(acc[7]) << 16) | (unsigned int)f2b(acc[6]);
        dstU[selfIdx] = o;
    }
}

// ---------------- BPR head ----------------
__global__ void __launch_bounds__(256) batch_kernel(
        const float* __restrict__ u0f, const float* __restrict__ i0f,
        const unsigned short* __restrict__ u1, const unsigned short* __restrict__ u2,
        const unsigned short* __restrict__ u3,
        const unsigned short* __restrict__ i1, const unsigned short* __restrict__ i2,
        const unsigned short* __restrict__ i3,
        const int* __restrict__ user, const int* __restrict__ ita, const int* __restrict__ itb,
        float* __restrict__ out, float* __restrict__ ls, float* __restrict__ l2a) {
    int wid = (blockIdx.x * 256 + threadIdx.x) >> 6;
    int lane = threadIdx.x & 63;
    if (wid >= BATCH) return;
    size_t uo = (size_t)user[wid] * FCT + lane;
    size_t ao = (size_t)ita[wid] * FCT + lane;
    size_t bo = (size_t)itb[wid] * FCT + lane;

    float pi, pj, l2;
    {
        float ue = u0f[uo], ie = i0f[ao], je = i0f[bo];
        pi = ue * ie; pj = ue * je; l2 = ue * ue + ie * ie + je * je;
    }
    const unsigned short* Ut[3] = {u1, u2, u3};
    const unsigned short* It[3] = {i1, i2, i3};
#pragma unroll
    for (int l = 0; l < 3; l++) {
        float ue = b2f(Ut[l][uo]), ie = b2f(It[l][ao]), je = b2f(It[l][bo]);
        pi += ue * ie;
        pj += ue * je;
        l2 += ue * ue + ie * ie + je * je;
    }
#pragma unroll
    for (int off = 32; off; off >>= 1) {
        pi += __shfl_xor(pi, off);
        pj += __shfl_xor(pj, off);
        l2 += __shfl_xor(l2, off);
    }
    if (lane == 0) {
        out[wid] = pi;
        out[BATCH + wid] = pj;
        float x = pi - pj;
        ls[wid] = fminf(x, 0.0f) - log1pf(expf(-fabsf(x)));
        l2a[wid] = 0.01f * l2;
    }
}

__global__ void final_kernel(const float* __restrict__ ls, const float* __restrict__ l2a,
                             float* __restrict__ out) {
    __shared__ float s1[256], s2[256];
    int t = threadIdx.x;
    float a = 0.f, b = 0.f;
    for (int i = t; i < BATCH; i += 256) {
        a += ls[i];
        b += l2a[i];
    }
    s1[t] = a;
    s2[t] = b;
    __syncthreads();
    for (int off = 128; off; off >>= 1) {
        if (t < off) {
            s1[t] += s1[t + off];
            s2[t] += s2[t + off];
        }
        __syncthreads();
    }
    if (t == 0) {
        float loss2 = -s1[0] / (float)BATCH;
        float l2m = s2[0] / (float)BATCH;
        out[2 * BATCH] = loss2 + l2m;
        out[2 * BATCH + 1] = loss2;
    }
}

// ---------------- launch ----------------
extern "C" void kernel_launch(void* const* d_in, const int* in_sizes, int n_in,
                              void* d_out, int out_size, void* d_ws, size_t ws_size,
                              hipStream_t stream) {
    const float* u0f = (const float*)d_in[0];
    const float* i0f = (const float*)d_in[1];
    const float* di  = (const float*)d_in[2];
    const float* dj  = (const float*)d_in[3];
    const float* vui = (const float*)d_in[4];
    const float* viu = (const float*)d_in[5];
    const int*   eu  = (const int*)d_in[6];
    const int*   ei  = (const int*)d_in[7];
    const int*   usr = (const int*)d_in[8];
    const int*   ita = (const int*)d_in[9];
    const int*   itb = (const int*)d_in[10];
    float* out = (float*)d_out;

    char* p = (char*)d_ws;
    auto alloc = [&](size_t bytes) -> char* {
        char* r = p;
        p += (bytes + 255) & ~(size_t)255;
        return r;
    };
    unsigned short* u0b = (unsigned short*)alloc((size_t)U_NUM * FCT * 2);
    unsigned short* u1b = (unsigned short*)alloc((size_t)U_NUM * FCT * 2);
    unsigned short* i0b = (unsigned short*)alloc((size_t)I_NUM * FCT * 2);
    unsigned short* i1b = (unsigned short*)alloc((size_t)I_NUM * FCT * 2);
    unsigned int* compact4   = (unsigned int*)alloc((size_t)TOTSLOTS * 4);    // 25.6 MB
    unsigned short* compactA = (unsigned short*)alloc((size_t)TOTSLOTS * 2);  // 12.8 MB
    unsigned int* staging4    = (unsigned int*)alloc((size_t)TOTSLOTS * 4);   // 25.6 MB
    unsigned char* staging_off = (unsigned char*)alloc((size_t)TOTSLOTS);     // 6.4 MB
    int* rowptr    = (int*)alloc((size_t)(NROWS + 1) * 4);
    int* cntmat256 = (int*)alloc((size_t)SUBS * NBUCK * 4);            // 2.4 MB
    int* localpfx  = (int*)alloc((size_t)NBUCK * SUBS * 4);            // 2.4 MB
    int* btot      = (int*)alloc((size_t)NBUCK * 4);
    int* bbase     = (int*)alloc((size_t)(NBUCK + 1) * 4);
    int* csum      = (int*)alloc((size_t)2048 * 4);
    int* cbase     = (int*)alloc((size_t)2049 * 4);
    float* ls      = (float*)alloc((size_t)BATCH * 4);
    float* l2a     = (float*)alloc((size_t)BATCH * 4);
    // overlays (disjoint lifetimes):
    //   csr4 <- compact4 ; i3b <- compactA ; u2b,u3b <- staging4 ; i2b <- staging_off
    unsigned int* csr4 = compact4;
    unsigned short* i3b = compactA;
    unsigned short* u2b = (unsigned short*)staging4;
    unsigned short* u3b = u2b + (size_t)U_NUM * FCT;
    unsigned short* i2b = (unsigned short*)staging_off;

    conv_kernel<<<(U_NUM * FCT / 4 + 255) / 256, 256, 0, stream>>>(u0f, u0b, U_NUM * FCT / 4);
    conv_kernel<<<(I_NUM * FCT / 4 + 255) / 256, 256, 0, stream>>>(i0f, i0b, I_NUM * FCT / 4);

    count256_kernel<<<SUBS, 256, 0, stream>>>(eu, ei, cntmat256);
    bscan2_kernel<<<NBUCK, 256, 0, stream>>>(cntmat256, localpfx, btot);
    bscan_kernel<<<1, 256, 0, stream>>>(btot, bbase);
    csum_kernel<<<8, 256, 0, stream>>>(cntmat256, csum);
    cbase_kernel<<<1, 256, 0, stream>>>(csum, cbase);

    cscatA_kernel<<<SUBS, 256, 0, stream>>>(eu, ei, vui, viu, cbase, compact4, compactA);
    scatterC_kernel<<<SUBS * 8, 256, 0, stream>>>(compact4, compactA, cntmat256, localpfx,
                                                  bbase, cbase, staging4, staging_off);
    rsort_kernel<<<NBUCK, 256, 0, stream>>>(bbase, staging4, staging_off, csr4, rowptr);

    int aggGrid = (NROWS * 64) / 256 + 1;
    agg_kernel<<<aggGrid, 256, 0, stream>>>(u0b, i0b, u1b, i1b, di, dj, rowptr, csr4);
    agg_kernel<<<aggGrid, 256, 0, stream>>>(u1b, i1b, u2b, i2b, di, dj, rowptr, csr4);
    agg_kernel<<<aggGrid, 256, 0, stream>>>(u2b, i2b, u3b, i3b, di, dj, rowptr, csr4);

    batch_kernel<<<(BATCH * 64) / 256, 256, 0, stream>>>(u0f, i0f, u1b, u2b, u3b,
                                                         i1b, i2b, i3b,
                                                         usr, ita, itb, out, ls, l2a);
    final_kernel<<<1, 256, 0, stream>>>(ls, l2a, out);
}

// Round 22
// 432.467 us; speedup vs baseline: 1.3977x; 1.0424x over previous
//
#include <hip/hip_runtime.h>

#define U_NUM   100000
#define I_NUM   50000
#define FCT     64
#define NEDGE   3200000
#define BATCH   16384
#define NROWS   (U_NUM + I_NUM)      // 150000
#define TOTSLOTS (2 * NEDGE)         // 6400000

#define BSH 6                        // 64 rows per bucket
#define NBU 1563                     // ceil(100000/64)
#define NBI 782                      // ceil(50000/64)
#define NBUCK (NBU + NBI)            // 2345
#define NQ   294                     // ceil(NBUCK/8) buckets per class
#define SUBS 256                     // slices
#define BUFSZ 4096                   // LDS payload slots (expected fill 3125)

__device__ __forceinline__ unsigned short f2b(float f) {
    unsigned int x = __float_as_uint(f);
    unsigned int r = (x + 0x7FFFu + ((x >> 16) & 1u)) >> 16;   // RNE
    return (unsigned short)r;
}
__device__ __forceinline__ float b2f(unsigned short u) {
    return __uint_as_float(((unsigned int)u) << 16);
}

// ---------------- fp32 -> bf16 table conversion ----------------
__global__ void conv_kernel(const float* __restrict__ in, unsigned short* __restrict__ out, int n4) {
    int t = blockIdx.x * blockDim.x + threadIdx.x;
    if (t >= n4) return;
    float4 v = *reinterpret_cast<const float4*>(in + (size_t)t * 4);
    ushort4 o;
    o.x = f2b(v.x); o.y = f2b(v.y); o.z = f2b(v.z); o.w = f2b(v.w);
    *reinterpret_cast<ushort4*>(out + (size_t)t * 4) = o;
}

// ---------------- single-sweep per-(sub,bucket) count (1024 thr: 4 waves/SIMD) ----------------
// Slice(sub) = {t : t = sub*1024 + tid + j*262144}. MUST match cscatA's iteration.
__global__ void __launch_bounds__(1024) count256_kernel(const int* __restrict__ eu,
                                                        const int* __restrict__ ei,
                                                        int* __restrict__ cntmat256) {
    __shared__ int lcnt[NBUCK];
    for (int k = threadIdx.x; k < NBUCK; k += 1024) lcnt[k] = 0;
    __syncthreads();
    int sub = blockIdx.x;
    for (int t = sub * 1024 + (int)threadIdx.x; t < NEDGE; t += SUBS * 1024) {
        int u = eu[t];
        int i = ei[t];
        atomicAdd(&lcnt[u >> BSH], 1);
        atomicAdd(&lcnt[NBU + (i >> BSH)], 1);
    }
    __syncthreads();
    int* row = cntmat256 + (size_t)sub * NBUCK;
    for (int k = threadIdx.x; k < NBUCK; k += 1024) row[k] = lcnt[k];
}

// ---------------- per-bucket scan over 256 subs -> localpfx + bucket total ----------------
__global__ void __launch_bounds__(256) bscan2_kernel(const int* __restrict__ cntmat256,
                                                     int* __restrict__ localpfx,
                                                     int* __restrict__ btot) {
    __shared__ int ws[4];
    int b = blockIdx.x;
    int t = threadIdx.x;
    int c = cntmat256[(size_t)t * NBUCK + b];
    int inc = c;
#pragma unroll
    for (int o = 1; o < 64; o <<= 1) {
        int x = __shfl_up(inc, o);
        if ((t & 63) >= o) inc += x;
    }
    if ((t & 63) == 63) ws[t >> 6] = inc;
    __syncthreads();
    int carry = 0;
#pragma unroll
    for (int w = 0; w < 4; w++) {
        if ((t >> 6) > w) carry += ws[w];
    }
    localpfx[(size_t)b * 256 + t] = carry + inc - c;   // exclusive prefix within bucket
    if (t == 255) btot[b] = carry + inc;               // bucket total
}

// ---------------- single-block exclusive scan over bucket totals -> bbase ----------------
__global__ void bscan_kernel(const int* __restrict__ btot, int* __restrict__ bbase) {
    __shared__ int s[256];
    int t = threadIdx.x;
    int v[10];                          // 256*10 = 2560 >= NBUCK
    int tot = 0;
#pragma unroll
    for (int k = 0; k < 10; k++) {
        int idx = t * 10 + k;
        v[k] = (idx < NBUCK) ? btot[idx] : 0;
        tot += v[k];
    }
    s[t] = tot;
    __syncthreads();
    for (int off = 1; off < 256; off <<= 1) {
        int x = (t >= off) ? s[t - off] : 0;
        __syncthreads();
        s[t] += x;
        __syncthreads();
    }
    int p = s[t] - tot;
#pragma unroll
    for (int k = 0; k < 10; k++) {
        int idx = t * 10 + k;
        if (idx < NBUCK) bbase[idx] = p;
        p += v[k];
    }
    if (t == 255) bbase[NBUCK] = TOTSLOTS;
}

// ---------------- per-(sub,cls) totals from cntmat256 ----------------
__global__ void __launch_bounds__(256) csum_kernel(const int* __restrict__ cntmat256,
                                                   int* __restrict__ csum) {
    int gid = blockIdx.x * 256 + threadIdx.x;   // 0..2047, sub-major: gid = sub*8+cls
    int sub = gid >> 3, cls = gid & 7;
    const int* row = cntmat256 + (size_t)sub * NBUCK;
    int s = 0;
    for (int q = 0; q < NQ; q++) {
        int b = q * 8 + cls;
        if (b < NBUCK) s += row[b];
    }
    csum[gid] = s;
}

// ---------------- exclusive scan over 2048 (sub,cls) totals -> cbase ----------------
__global__ void cbase_kernel(const int* __restrict__ csum, int* __restrict__ cbase) {
    __shared__ int s[256];
    int t = threadIdx.x;
    int v[8];
    int tot = 0;
#pragma unroll
    for (int k = 0; k < 8; k++) {
        v[k] = csum[t * 8 + k];
        tot += v[k];
    }
    s[t] = tot;
    __syncthreads();
    for (int off = 1; off < 256; off <<= 1) {
        int x = (t >= off) ? s[t - off] : 0;
        __syncthreads();
        s[t] += x;
        __syncthreads();
    }
    int p = s[t] - tot;
#pragma unroll
    for (int k = 0; k < 8; k++) {
        cbase[t * 8 + k] = p;
        p += v[k];
    }
    if (t == 255) cbase[2048] = TOTSLOTS;
}

// ---------------- phase A: 1x sweep, compact edges into per-(sub,cls) regions ----------------
// 1024 thr (4 waves/SIMD for latency hiding). Iteration pattern MUST equal count256's.
__global__ void __launch_bounds__(1024) cscatA_kernel(const int* __restrict__ eu,
                                                      const int* __restrict__ ei,
                                                      const float* __restrict__ vui,
                                                      const float* __restrict__ viu,
                                                      const int* __restrict__ cbase,
                                                      unsigned int* __restrict__ compact4,
                                                      unsigned short* __restrict__ compactA) {
    __shared__ int lbase8[8];
    __shared__ int lcnt8[8];
    int sub = blockIdx.x;
    if (threadIdx.x < 8) {
        lbase8[threadIdx.x] = cbase[sub * 8 + (int)threadIdx.x];
        lcnt8[threadIdx.x] = 0;
    }
    __syncthreads();
    for (int t = sub * 1024 + (int)threadIdx.x; t < NEDGE; t += SUBS * 1024) {
        int u = eu[t];
        int i = ei[t];
        float va = vui[t];
        float vb = viu[t];
        int bu = u >> BSH;
        int cls = bu & 7;
        int r = atomicAdd(&lcnt8[cls], 1);
        int pos = lbase8[cls] + r;
        compact4[pos] = ((unsigned int)i << 15) | ((unsigned int)f2b(va) & 0x7FFFu);
        compactA[pos] = (unsigned short)((((unsigned int)(bu >> 3)) << 6) | (unsigned int)(u & 63));
        int bid = NBU + (i >> BSH);
        int cls2 = bid & 7;
        int r2 = atomicAdd(&lcnt8[cls2], 1);
        int pos2 = lbase8[cls2] + r2;
        compact4[pos2] = ((unsigned int)u << 15) | ((unsigned int)f2b(vb) & 0x7FFFu);
        compactA[pos2] = (unsigned short)((((unsigned int)(bid >> 3)) << 6) | (unsigned int)(i & 63));
    }
}

// ---------------- phase B: per-(cls,sub) region -> bucket-ordered staging ----------------
__global__ void __launch_bounds__(256) scatterC_kernel(const unsigned int* __restrict__ compact4,
                                                       const unsigned short* __restrict__ compactA,
                                                       const int* __restrict__ cntmat256,
                                                       const int* __restrict__ localpfx,
                                                       const int* __restrict__ bbase,
                                                       const int* __restrict__ cbase,
                                                       unsigned int* __restrict__ staging4,
                                                       unsigned char* __restrict__ staging_off) {
    __shared__ int lofs[NQ + 1];
    __shared__ int lbase[NQ];
    __shared__ int lrank[NQ];
    __shared__ unsigned int lbuf4[BUFSZ];       // 16 KB
    __shared__ unsigned char lbufo[BUFSZ];      // 4 KB
    int cls = blockIdx.x & 7;
    int sub = blockIdx.x >> 3;
    for (int k = threadIdx.x; k < NQ; k += 256) {
        int b = k * 8 + cls;
        if (b < NBUCK) {
            lbase[k] = bbase[b] + localpfx[(size_t)b * 256 + sub];
            lofs[k + 1] = cntmat256[(size_t)sub * NBUCK + b];
        } else {
            lbase[k] = 0;
            lofs[k + 1] = 0;
        }
        lrank[k] = 0;
    }
    if (threadIdx.x == 0) lofs[0] = 0;
    __syncthreads();
    if (threadIdx.x < 64) {
        int carry = 0;
        for (int c = 0; c < 5; c++) {
            int idx = c * 64 + (int)threadIdx.x + 1;
            int v = (idx <= NQ) ? lofs[idx] : 0;
            int inc = v;
#pragma unroll
            for (int o = 1; o < 64; o <<= 1) {
                int x = __shfl_up(inc, o);
                if ((int)threadIdx.x >= o) inc += x;
            }
            if (idx <= NQ) lofs[idx] = carry + inc;
            carry += __shfl(inc, 63);
        }
    }
    __syncthreads();
    int total = lofs[NQ];
    int rbeg = cbase[sub * 8 + cls], rend = cbase[sub * 8 + cls + 1];
    for (int e = rbeg + (int)threadIdx.x; e < rend; e += 256) {
        unsigned int pay = compact4[e];
        unsigned int a = compactA[e];
        int q = (int)(a >> 6);
        unsigned char off = (unsigned char)(a & 63u);
        int r = atomicAdd(&lrank[q], 1);
        int pos = lofs[q] + r;
        if (pos < BUFSZ) { lbuf4[pos] = pay; lbufo[pos] = off; }
        else { staging4[lbase[q] + r] = pay; staging_off[lbase[q] + r] = off; }
    }
    __syncthreads();
    int fl = min(total, BUFSZ);
    for (int t = threadIdx.x; t < fl; t += 256) {
        int lo = 0, hi = NQ;
        while (hi - lo > 1) {
            int mid = (lo + hi) >> 1;
            if (lofs[mid] <= t) lo = mid; else hi = mid;
        }
        int g = lbase[lo] + (t - lofs[lo]);
        staging4[g] = lbuf4[t];
        staging_off[g] = lbufo[t];
    }
}

// ---------------- phase C: row counts -> rowptr -> row-ordered csr (direct copy) ----------------
__global__ void __launch_bounds__(256) rsort_kernel(const int* __restrict__ bbase,
                                                    const unsigned int* __restrict__ staging4,
                                                    const unsigned char* __restrict__ staging_off,
                                                    unsigned int* __restrict__ csr4,
                                                    int* __restrict__ rowptr) {
    __shared__ int fillr[64];
    __shared__ int rp[64];
    int b = blockIdx.x;
    int gRowBase, rows;
    if (b < NBU) {
        gRowBase = b << BSH;
        rows = min(64, U_NUM - gRowBase);
    } else {
        int rb = (b - NBU) << BSH;
        gRowBase = U_NUM + rb;
        rows = min(64, I_NUM - rb);
    }
    if (threadIdx.x < 64) fillr[threadIdx.x] = 0;
    __syncthreads();
    int beg = bbase[b], end = bbase[b + 1];
    for (int e = beg + (int)threadIdx.x; e < end; e += 256) {
        atomicAdd(&fillr[staging_off[e]], 1);
    }
    __syncthreads();
    if (threadIdx.x < 64) {
        int c = fillr[threadIdx.x];
        int inc = c;
#pragma unroll
        for (int o = 1; o < 64; o <<= 1) {
            int x = __shfl_up(inc, o);
            if ((int)threadIdx.x >= o) inc += x;
        }
        int excl = beg + inc - c;
        rp[threadIdx.x] = excl;
        if ((int)threadIdx.x < rows) rowptr[gRowBase + threadIdx.x] = excl;
        fillr[threadIdx.x] = 0;
    }
    if (b == 0 && threadIdx.x == 64) rowptr[NROWS] = TOTSLOTS;
    __syncthreads();
    for (int e = beg + (int)threadIdx.x; e < end; e += 256) {
        int off = staging_off[e];
        int dst = rp[off] + atomicAdd(&fillr[off], 1);
        csr4[dst] = staging4[e];
    }
}

// ---------------- propagation: eighth-wave per edge, uint4 per lane, 4 gathers in flight ----------------
__global__ void __launch_bounds__(256) agg_kernel(
        const unsigned short* __restrict__ uprev, const unsigned short* __restrict__ iprev,
        unsigned short* __restrict__ unext, unsigned short* __restrict__ inext,
        const float* __restrict__ di, const float* __restrict__ dj,
        const int* __restrict__ rowptr, const unsigned int* __restrict__ csr4) {
    int wid = (blockIdx.x * 256 + threadIdx.x) >> 6;
    int lane = threadIdx.x & 63;
    if (wid >= NROWS) return;
    int slot = lane >> 3;                          // edge slot 0..7
    unsigned int dq = (unsigned int)(lane & 7);    // uint4 index within row
    const uint4* selfU;
    const uint4* srcU;
    uint4* dstU;
    float dscale;
    unsigned int r32;
    if (wid < U_NUM) {
        r32 = (unsigned int)wid;
        selfU = (const uint4*)uprev;
        srcU  = (const uint4*)iprev;
        dstU  = (uint4*)unext;
        dscale = di[wid];
    } else {
        r32 = (unsigned int)(wid - U_NUM);
        selfU = (const uint4*)iprev;
        srcU  = (const uint4*)uprev;
        dstU  = (uint4*)inext;
        dscale = dj[wid - U_NUM];
    }
    int beg = rowptr[wid], end = rowptr[wid + 1];
    unsigned int selfIdx = (r32 << 3) | dq;
    float acc[8];
    {
        uint4 s = selfU[selfIdx];
        bool first = (slot == 0);
        unsigned int sw[4] = {s.x, s.y, s.z, s.w};
#pragma unroll
        for (int d = 0; d < 4; d++) {
            acc[2 * d]     = first ? b2f((unsigned short)(sw[d] & 0xFFFFu)) * dscale : 0.0f;
            acc[2 * d + 1] = first ? b2f((unsigned short)(sw[d] >> 16)) * dscale : 0.0f;
        }
    }
    int e = beg;
    for (; e + 32 <= end; e += 32) {
        unsigned int pk[4];
        uint4 g[4];
#pragma unroll
        for (int k = 0; k < 4; k++) pk[k] = csr4[e + 8 * k + slot];
#pragma unroll
        for (int k = 0; k < 4; k++) g[k] = srcU[((pk[k] >> 15) << 3) | dq];
#pragma unroll
        for (int k = 0; k < 4; k++) {
            float w = b2f((unsigned short)(pk[k] & 0x7FFFu));
            unsigned int gw[4] = {g[k].x, g[k].y, g[k].z, g[k].w};
#pragma unroll
            for (int d = 0; d < 4; d++) {
                acc[2 * d]     = fmaf(w, b2f((unsigned short)(gw[d] & 0xFFFFu)), acc[2 * d]);
                acc[2 * d + 1] = fmaf(w, b2f((unsigned short)(gw[d] >> 16)), acc[2 * d + 1]);
            }
        }
    }
    if (e + 16 <= end) {
        unsigned int pk[2];
        uint4 g[2];
#pragma unroll
        for (int k = 0; k < 2; k++) pk[k] = csr4[e + 8 * k + slot];
#pragma unroll
        for (int k = 0; k < 2; k++) g[k] = srcU[((pk[k] >> 15) << 3) | dq];
#pragma unroll
        for (int k = 0; k < 2; k++) {
            float w = b2f((unsigned short)(pk[k] & 0x7FFFu));
            unsigned int gw[4] = {g[k].x, g[k].y, g[k].z, g[k].w};
#pragma unroll
            for (int d = 0; d < 4; d++) {
                acc[2 * d]     = fmaf(w, b2f((unsigned short)(gw[d] & 0xFFFFu)), acc[2 * d]);
                acc[2 * d + 1] = fmaf(w, b2f((unsigned short)(gw[d] >> 16)), acc[2 * d + 1]);
            }
        }
        e += 16;
    }
    for (; e < end; e += 8) {
        int idx = e + slot;
        if (idx < end) {
            unsigned int pk = csr4[idx];
            uint4 g = srcU[((pk >> 15) << 3) | dq];
            float w = b2f((unsigned short)(pk & 0x7FFFu));
            unsigned int gw[4] = {g.x, g.y, g.z, g.w};
#pragma unroll
            for (int d = 0; d < 4; d++) {
                acc[2 * d]     = fmaf(w, b2f((unsigned short)(gw[d] & 0xFFFFu)), acc[2 * d]);
                acc[2 * d + 1] = fmaf(w, b2f((unsigned short)(gw[d] >> 16)), acc[2 * d + 1]);
            }
        }
    }
#pragma unroll
    for (int d = 0; d < 8; d++) {
        acc[d] += __shfl_xor(acc[d], 8);
        acc[d] += __shfl_xor(acc[d], 16);
        acc[d] += __shfl_xor(acc[d], 32);
    }
    if (slot == 0) {
        uint4 o;
        o.x = ((unsigned int)f2b(acc[1]) << 16) | (unsigned int)f2b(acc[0]);
        o.y = ((unsigned int)f2b(acc[3]) << 16) | (unsigned int)f2b(acc[2]);
        o.z = ((unsigned int)f2b(acc[5]) << 16) | (unsigned int)f2b(acc[4]);
        o.w = ((unsigned int)f2b(acc[7]) << 16) | (unsigned int)f2b(acc[6]);
        dstU[selfIdx] = o;
    }
}

// ---------------- BPR head ----------------
__global__ void __launch_bounds__(256) batch_kernel(
        const float* __restrict__ u0f, const float* __restrict__ i0f,
        const unsigned short* __restrict__ u1, const unsigned short* __restrict__ u2,
        const unsigned short* __restrict__ u3,
        const unsigned short* __restrict__ i1, const unsigned short* __restrict__ i2,
        const unsigned short* __restrict__ i3,
        const int* __restrict__ user, const int* __restrict__ ita, const int* __restrict__ itb,
        float* __restrict__ out, float* __restrict__ ls, float* __restrict__ l2a) {
    int wid = (blockIdx.x * 256 + threadIdx.x) >> 6;
    int lane = threadIdx.x & 63;
    if (wid >= BATCH) return;
    size_t uo = (size_t)user[wid] * FCT + lane;
    size_t ao = (size_t)ita[wid] * FCT + lane;
    size_t bo = (size_t)itb[wid] * FCT + lane;

    float pi, pj, l2;
    {
        float ue = u0f[uo], ie = i0f[ao], je = i0f[bo];
        pi = ue * ie; pj = ue * je; l2 = ue * ue + ie * ie + je * je;
    }
    const unsigned short* Ut[3] = {u1, u2, u3};
    const unsigned short* It[3] = {i1, i2, i3};
#pragma unroll
    for (int l = 0; l < 3; l++) {
        float ue = b2f(Ut[l][uo]), ie = b2f(It[l][ao]), je = b2f(It[l][bo]);
        pi += ue * ie;
        pj += ue * je;
        l2 += ue * ue + ie * ie + je * je;
    }
#pragma unroll
    for (int off = 32; off; off >>= 1) {
        pi += __shfl_xor(pi, off);
        pj += __shfl_xor(pj, off);
        l2 += __shfl_xor(l2, off);
    }
    if (lane == 0) {
        out[wid] = pi;
        out[BATCH + wid] = pj;
        float x = pi - pj;
        ls[wid] = fminf(x, 0.0f) - log1pf(expf(-fabsf(x)));
        l2a[wid] = 0.01f * l2;
    }
}

__global__ void final_kernel(const float* __restrict__ ls, const float* __restrict__ l2a,
                             float* __restrict__ out) {
    __shared__ float s1[256], s2[256];
    int t = threadIdx.x;
    float a = 0.f, b = 0.f;
    for (int i = t; i < BATCH; i += 256) {
        a += ls[i];
        b += l2a[i];
    }
    s1[t] = a;
    s2[t] = b;
    __syncthreads();
    for (int off = 128; off; off >>= 1) {
        if (t < off) {
            s1[t] += s1[t + off];
            s2[t] += s2[t + off];
        }
        __syncthreads();
    }
    if (t == 0) {
        float loss2 = -s1[0] / (float)BATCH;
        float l2m = s2[0] / (float)BATCH;
        out[2 * BATCH] = loss2 + l2m;
        out[2 * BATCH + 1] = loss2;
    }
}

// ---------------- launch ----------------
extern "C" void kernel_launch(void* const* d_in, const int* in_sizes, int n_in,
                              void* d_out, int out_size, void* d_ws, size_t ws_size,
                              hipStream_t stream) {
    const float* u0f = (const float*)d_in[0];
    const float* i0f = (const float*)d_in[1];
    const float* di  = (const float*)d_in[2];
    const float* dj  = (const float*)d_in[3];
    const float* vui = (const float*)d_in[4];
    const float* viu = (const float*)d_in[5];
    const int*   eu  = (const int*)d_in[6];
    const int*   ei  = (const int*)d_in[7];
    const int*   usr = (const int*)d_in[8];
    const int*   ita = (const int*)d_in[9];
    const int*   itb = (const int*)d_in[10];
    float* out = (float*)d_out;

    char* p = (char*)d_ws;
    auto alloc = [&](size_t bytes) -> char* {
        char* r = p;
        p += (bytes + 255) & ~(size_t)255;
        return r;
    };
    unsigned short* u0b = (unsigned short*)alloc((size_t)U_NUM * FCT * 2);
    unsigned short* u1b = (unsigned short*)alloc((size_t)U_NUM * FCT * 2);
    unsigned short* i0b = (unsigned short*)alloc((size_t)I_NUM * FCT * 2);
    unsigned short* i1b = (unsigned short*)alloc((size_t)I_NUM * FCT * 2);
    unsigned int* compact4   = (unsigned int*)alloc((size_t)TOTSLOTS * 4);    // 25.6 MB
    unsigned short* compactA = (unsigned short*)alloc((size_t)TOTSLOTS * 2);  // 12.8 MB
    unsigned int* staging4    = (unsigned int*)alloc((size_t)TOTSLOTS * 4);   // 25.6 MB
    unsigned char* staging_off = (unsigned char*)alloc((size_t)TOTSLOTS);     // 6.4 MB
    int* rowptr    = (int*)alloc((size_t)(NROWS + 1) * 4);
    int* cntmat256 = (int*)alloc((size_t)SUBS * NBUCK * 4);            // 2.4 MB
    int* localpfx  = (int*)alloc((size_t)NBUCK * SUBS * 4);            // 2.4 MB
    int* btot      = (int*)alloc((size_t)NBUCK * 4);
    int* bbase     = (int*)alloc((size_t)(NBUCK + 1) * 4);
    int* csum      = (int*)alloc((size_t)2048 * 4);
    int* cbase     = (int*)alloc((size_t)2049 * 4);
    float* ls      = (float*)alloc((size_t)BATCH * 4);
    float* l2a     = (float*)alloc((size_t)BATCH * 4);
    // overlays (disjoint lifetimes):
    //   csr4 <- compact4 ; i3b <- compactA ; u2b,u3b <- staging4 ; i2b <- staging_off
    unsigned int* csr4 = compact4;
    unsigned short* i3b = compactA;
    unsigned short* u2b = (unsigned short*)staging4;
    unsigned short* u3b = u2b + (size_t)U_NUM * FCT;
    unsigned short* i2b = (unsigned short*)staging_off;

    conv_kernel<<<(U_NUM * FCT / 4 + 255) / 256, 256, 0, stream>>>(u0f, u0b, U_NUM * FCT / 4);
    conv_kernel<<<(I_NUM * FCT / 4 + 255) / 256, 256, 0, stream>>>(i0f, i0b, I_NUM * FCT / 4);

    count256_kernel<<<SUBS, 1024, 0, stream>>>(eu, ei, cntmat256);
    bscan2_kernel<<<NBUCK, 256, 0, stream>>>(cntmat256, localpfx, btot);
    bscan_kernel<<<1, 256, 0, stream>>>(btot, bbase);
    csum_kernel<<<8, 256, 0, stream>>>(cntmat256, csum);
    cbase_kernel<<<1, 256, 0, stream>>>(csum, cbase);

    cscatA_kernel<<<SUBS, 1024, 0, stream>>>(eu, ei, vui, viu, cbase, compact4, compactA);
    scatterC_kernel<<<SUBS * 8, 256, 0, stream>>>(compact4, compactA, cntmat256, localpfx,
                                                  bbase, cbase, staging4, staging_off);
    rsort_kernel<<<NBUCK, 256, 0, stream>>>(bbase, staging4, staging_off, csr4, rowptr);

    int aggGrid = (NROWS * 64) / 256 + 1;
    agg_kernel<<<aggGrid, 256, 0, stream>>>(u0b, i0b, u1b, i1b, di, dj, rowptr, csr4);
    agg_kernel<<<aggGrid, 256, 0, stream>>>(u1b, i1b, u2b, i2b, di, dj, rowptr, csr4);
    agg_kernel<<<aggGrid, 256, 0, stream>>>(u2b, i2b, u3b, i3b, di, dj, rowptr, csr4);

    batch_kernel<<<(BATCH * 64) / 256, 256, 0, stream>>>(u0f, i0f, u1b, u2b, u3b,
                                                         i1b, i2b, i3b,
                                                         usr, ita, itb, out, ls, l2a);
    final_kernel<<<1, 256, 0, stream>>>(ls, l2a, out);
}

// Round 23
// 426.411 us; speedup vs baseline: 1.4175x; 1.0142x over previous
//
#include <hip/hip_runtime.h>

#define U_NUM   100000
#define I_NUM   50000
#define FCT     64
#define NEDGE   3200000
#define BATCH   16384
#define NROWS   (U_NUM + I_NUM)      // 150000
#define TOTSLOTS (2 * NEDGE)         // 6400000

#define BSH 6                        // 64 rows per bucket
#define NBU 1563                     // ceil(100000/64)
#define NBI 782                      // ceil(50000/64)
#define NBUCK (NBU + NBI)            // 2345
#define NQ   294                     // ceil(NBUCK/8) buckets per class
#define SUBS 256                     // slices
#define BUFSZ 4096                   // LDS payload slots (expected fill 3125)

__device__ __forceinline__ unsigned short f2b(float f) {
    unsigned int x = __float_as_uint(f);
    unsigned int r = (x + 0x7FFFu + ((x >> 16) & 1u)) >> 16;   // RNE
    return (unsigned short)r;
}
__device__ __forceinline__ float b2f(unsigned short u) {
    return __uint_as_float(((unsigned int)u) << 16);
}

// ---------------- fp32 -> bf16 conversion, both tables in one launch ----------------
__global__ void conv_kernel(const float* __restrict__ uin, const float* __restrict__ iin,
                            unsigned short* __restrict__ uout, unsigned short* __restrict__ iout) {
    int t = blockIdx.x * blockDim.x + threadIdx.x;
    const int U4 = U_NUM * FCT / 4;
    const int T4 = NROWS * FCT / 4;
    if (t >= T4) return;
    const float* in;
    unsigned short* out;
    int idx;
    if (t < U4) { in = uin; out = uout; idx = t; }
    else        { in = iin; out = iout; idx = t - U4; }
    float4 v = *reinterpret_cast<const float4*>(in + (size_t)idx * 4);
    ushort4 o;
    o.x = f2b(v.x); o.y = f2b(v.y); o.z = f2b(v.z); o.w = f2b(v.w);
    *reinterpret_cast<ushort4*>(out + (size_t)idx * 4) = o;
}

// ---------------- single-sweep per-(sub,bucket) count (1024 thr: 4 waves/SIMD) ----------------
// Slice(sub) = {t : t = sub*1024 + tid + j*262144}. MUST match cscatA's iteration.
__global__ void __launch_bounds__(1024) count256_kernel(const int* __restrict__ eu,
                                                        const int* __restrict__ ei,
                                                        int* __restrict__ cntmat256) {
    __shared__ int lcnt[NBUCK];
    for (int k = threadIdx.x; k < NBUCK; k += 1024) lcnt[k] = 0;
    __syncthreads();
    int sub = blockIdx.x;
    for (int t = sub * 1024 + (int)threadIdx.x; t < NEDGE; t += SUBS * 1024) {
        int u = eu[t];
        int i = ei[t];
        atomicAdd(&lcnt[u >> BSH], 1);
        atomicAdd(&lcnt[NBU + (i >> BSH)], 1);
    }
    __syncthreads();
    int* row = cntmat256 + (size_t)sub * NBUCK;
    for (int k = threadIdx.x; k < NBUCK; k += 1024) row[k] = lcnt[k];
}

// ---------------- per-bucket scan over 256 subs -> localpfx + bucket total ----------------
__global__ void __launch_bounds__(256) bscan2_kernel(const int* __restrict__ cntmat256,
                                                     int* __restrict__ localpfx,
                                                     int* __restrict__ btot) {
    __shared__ int ws[4];
    int b = blockIdx.x;
    int t = threadIdx.x;
    int c = cntmat256[(size_t)t * NBUCK + b];
    int inc = c;
#pragma unroll
    for (int o = 1; o < 64; o <<= 1) {
        int x = __shfl_up(inc, o);
        if ((t & 63) >= o) inc += x;
    }
    if ((t & 63) == 63) ws[t >> 6] = inc;
    __syncthreads();
    int carry = 0;
#pragma unroll
    for (int w = 0; w < 4; w++) {
        if ((t >> 6) > w) carry += ws[w];
    }
    localpfx[(size_t)b * 256 + t] = carry + inc - c;   // exclusive prefix within bucket
    if (t == 255) btot[b] = carry + inc;               // bucket total
}

// ---------------- single-block exclusive scan over bucket totals -> bbase ----------------
__global__ void bscan_kernel(const int* __restrict__ btot, int* __restrict__ bbase) {
    __shared__ int s[256];
    int t = threadIdx.x;
    int v[10];                          // 256*10 = 2560 >= NBUCK
    int tot = 0;
#pragma unroll
    for (int k = 0; k < 10; k++) {
        int idx = t * 10 + k;
        v[k] = (idx < NBUCK) ? btot[idx] : 0;
        tot += v[k];
    }
    s[t] = tot;
    __syncthreads();
    for (int off = 1; off < 256; off <<= 1) {
        int x = (t >= off) ? s[t - off] : 0;
        __syncthreads();
        s[t] += x;
        __syncthreads();
    }
    int p = s[t] - tot;
#pragma unroll
    for (int k = 0; k < 10; k++) {
        int idx = t * 10 + k;
        if (idx < NBUCK) bbase[idx] = p;
        p += v[k];
    }
    if (t == 255) bbase[NBUCK] = TOTSLOTS;
}

// ---------------- per-(sub,cls) totals from cntmat256 ----------------
__global__ void __launch_bounds__(256) csum_kernel(const int* __restrict__ cntmat256,
                                                   int* __restrict__ csum) {
    int gid = blockIdx.x * 256 + threadIdx.x;   // 0..2047, sub-major: gid = sub*8+cls
    int sub = gid >> 3, cls = gid & 7;
    const int* row = cntmat256 + (size_t)sub * NBUCK;
    int s = 0;
    for (int q = 0; q < NQ; q++) {
        int b = q * 8 + cls;
        if (b < NBUCK) s += row[b];
    }
    csum[gid] = s;
}

// ---------------- exclusive scan over 2048 (sub,cls) totals -> cbase ----------------
__global__ void cbase_kernel(const int* __restrict__ csum, int* __restrict__ cbase) {
    __shared__ int s[256];
    int t = threadIdx.x;
    int v[8];
    int tot = 0;
#pragma unroll
    for (int k = 0; k < 8; k++) {
        v[k] = csum[t * 8 + k];
        tot += v[k];
    }
    s[t] = tot;
    __syncthreads();
    for (int off = 1; off < 256; off <<= 1) {
        int x = (t >= off) ? s[t - off] : 0;
        __syncthreads();
        s[t] += x;
        __syncthreads();
    }
    int p = s[t] - tot;
#pragma unroll
    for (int k = 0; k < 8; k++) {
        cbase[t * 8 + k] = p;
        p += v[k];
    }
    if (t == 255) cbase[2048] = TOTSLOTS;
}

// ---------------- phase A: 1x sweep, compact edges into per-(sub,cls) regions ----------------
__global__ void __launch_bounds__(1024) cscatA_kernel(const int* __restrict__ eu,
                                                      const int* __restrict__ ei,
                                                      const float* __restrict__ vui,
                                                      const float* __restrict__ viu,
                                                      const int* __restrict__ cbase,
                                                      unsigned int* __restrict__ compact4,
                                                      unsigned short* __restrict__ compactA) {
    __shared__ int lbase8[8];
    __shared__ int lcnt8[8];
    int sub = blockIdx.x;
    if (threadIdx.x < 8) {
        lbase8[threadIdx.x] = cbase[sub * 8 + (int)threadIdx.x];
        lcnt8[threadIdx.x] = 0;
    }
    __syncthreads();
    for (int t = sub * 1024 + (int)threadIdx.x; t < NEDGE; t += SUBS * 1024) {
        int u = eu[t];
        int i = ei[t];
        float va = vui[t];
        float vb = viu[t];
        int bu = u >> BSH;
        int cls = bu & 7;
        int r = atomicAdd(&lcnt8[cls], 1);
        int pos = lbase8[cls] + r;
        compact4[pos] = ((unsigned int)i << 15) | ((unsigned int)f2b(va) & 0x7FFFu);
        compactA[pos] = (unsigned short)((((unsigned int)(bu >> 3)) << 6) | (unsigned int)(u & 63));
        int bid = NBU + (i >> BSH);
        int cls2 = bid & 7;
        int r2 = atomicAdd(&lcnt8[cls2], 1);
        int pos2 = lbase8[cls2] + r2;
        compact4[pos2] = ((unsigned int)u << 15) | ((unsigned int)f2b(vb) & 0x7FFFu);
        compactA[pos2] = (unsigned short)((((unsigned int)(bid >> 3)) << 6) | (unsigned int)(i & 63));
    }
}

// ---------------- phase B: per-(cls,sub) region -> bucket-ordered staging ----------------
__global__ void __launch_bounds__(256) scatterC_kernel(const unsigned int* __restrict__ compact4,
                                                       const unsigned short* __restrict__ compactA,
                                                       const int* __restrict__ cntmat256,
                                                       const int* __restrict__ localpfx,
                                                       const int* __restrict__ bbase,
                                                       const int* __restrict__ cbase,
                                                       unsigned int* __restrict__ staging4,
                                                       unsigned char* __restrict__ staging_off) {
    __shared__ int lofs[NQ + 1];
    __shared__ int lbase[NQ];
    __shared__ int lrank[NQ];
    __shared__ unsigned int lbuf4[BUFSZ];       // 16 KB
    __shared__ unsigned char lbufo[BUFSZ];      // 4 KB
    int cls = blockIdx.x & 7;
    int sub = blockIdx.x >> 3;
    for (int k = threadIdx.x; k < NQ; k += 256) {
        int b = k * 8 + cls;
        if (b < NBUCK) {
            lbase[k] = bbase[b] + localpfx[(size_t)b * 256 + sub];
            lofs[k + 1] = cntmat256[(size_t)sub * NBUCK + b];
        } else {
            lbase[k] = 0;
            lofs[k + 1] = 0;
        }
        lrank[k] = 0;
    }
    if (threadIdx.x == 0) lofs[0] = 0;
    __syncthreads();
    if (threadIdx.x < 64) {
        int carry = 0;
        for (int c = 0; c < 5; c++) {
            int idx = c * 64 + (int)threadIdx.x + 1;
            int v = (idx <= NQ) ? lofs[idx] : 0;
            int inc = v;
#pragma unroll
            for (int o = 1; o < 64; o <<= 1) {
                int x = __shfl_up(inc, o);
                if ((int)threadIdx.x >= o) inc += x;
            }
            if (idx <= NQ) lofs[idx] = carry + inc;
            carry += __shfl(inc, 63);
        }
    }
    __syncthreads();
    int total = lofs[NQ];
    int rbeg = cbase[sub * 8 + cls], rend = cbase[sub * 8 + cls + 1];
    for (int e = rbeg + (int)threadIdx.x; e < rend; e += 256) {
        unsigned int pay = compact4[e];
        unsigned int a = compactA[e];
        int q = (int)(a >> 6);
        unsigned char off = (unsigned char)(a & 63u);
        int r = atomicAdd(&lrank[q], 1);
        int pos = lofs[q] + r;
        if (pos < BUFSZ) { lbuf4[pos] = pay; lbufo[pos] = off; }
        else { staging4[lbase[q] + r] = pay; staging_off[lbase[q] + r] = off; }
    }
    __syncthreads();
    int fl = min(total, BUFSZ);
    for (int t = threadIdx.x; t < fl; t += 256) {
        int lo = 0, hi = NQ;
        while (hi - lo > 1) {
            int mid = (lo + hi) >> 1;
            if (lofs[mid] <= t) lo = mid; else hi = mid;
        }
        int g = lbase[lo] + (t - lofs[lo]);
        staging4[g] = lbuf4[t];
        staging_off[g] = lbufo[t];
    }
}

// ---------------- phase C: row counts -> rowptr -> row-ordered csr (512 thr) ----------------
__global__ void __launch_bounds__(512) rsort_kernel(const int* __restrict__ bbase,
                                                    const unsigned int* __restrict__ staging4,
                                                    const unsigned char* __restrict__ staging_off,
                                                    unsigned int* __restrict__ csr4,
                                                    int* __restrict__ rowptr) {
    __shared__ int fillr[64];
    __shared__ int rp[64];
    int b = blockIdx.x;
    int gRowBase, rows;
    if (b < NBU) {
        gRowBase = b << BSH;
        rows = min(64, U_NUM - gRowBase);
    } else {
        int rb = (b - NBU) << BSH;
        gRowBase = U_NUM + rb;
        rows = min(64, I_NUM - rb);
    }
    if (threadIdx.x < 64) fillr[threadIdx.x] = 0;
    __syncthreads();
    int beg = bbase[b], end = bbase[b + 1];
    for (int e = beg + (int)threadIdx.x; e < end; e += 512) {
        atomicAdd(&fillr[staging_off[e]], 1);
    }
    __syncthreads();
    if (threadIdx.x < 64) {
        int c = fillr[threadIdx.x];
        int inc = c;
#pragma unroll
        for (int o = 1; o < 64; o <<= 1) {
            int x = __shfl_up(inc, o);
            if ((int)threadIdx.x >= o) inc += x;
        }
        int excl = beg + inc - c;
        rp[threadIdx.x] = excl;
        if ((int)threadIdx.x < rows) rowptr[gRowBase + threadIdx.x] = excl;
        fillr[threadIdx.x] = 0;
    }
    if (b == 0 && threadIdx.x == 64) rowptr[NROWS] = TOTSLOTS;
    __syncthreads();
    for (int e = beg + (int)threadIdx.x; e < end; e += 512) {
        int off = staging_off[e];
        int dst = rp[off] + atomicAdd(&fillr[off], 1);
        csr4[dst] = staging4[e];
    }
}

// ---------------- propagation: eighth-wave per edge, uint4 per lane, 4 gathers in flight ----------------
__global__ void __launch_bounds__(256) agg_kernel(
        const unsigned short* __restrict__ uprev, const unsigned short* __restrict__ iprev,
        unsigned short* __restrict__ unext, unsigned short* __restrict__ inext,
        const float* __restrict__ di, const float* __restrict__ dj,
        const int* __restrict__ rowptr, const unsigned int* __restrict__ csr4) {
    int wid = (blockIdx.x * 256 + threadIdx.x) >> 6;
    int lane = threadIdx.x & 63;
    if (wid >= NROWS) return;
    int slot = lane >> 3;                          // edge slot 0..7
    unsigned int dq = (unsigned int)(lane & 7);    // uint4 index within row
    const uint4* selfU;
    const uint4* srcU;
    uint4* dstU;
    float dscale;
    unsigned int r32;
    if (wid < U_NUM) {
        r32 = (unsigned int)wid;
        selfU = (const uint4*)uprev;
        srcU  = (const uint4*)iprev;
        dstU  = (uint4*)unext;
        dscale = di[wid];
    } else {
        r32 = (unsigned int)(wid - U_NUM);
        selfU = (const uint4*)iprev;
        srcU  = (const uint4*)uprev;
        dstU  = (uint4*)inext;
        dscale = dj[wid - U_NUM];
    }
    int beg = rowptr[wid], end = rowptr[wid + 1];
    unsigned int selfIdx = (r32 << 3) | dq;
    float acc[8];
    {
        uint4 s = selfU[selfIdx];
        bool first = (slot == 0);
        unsigned int sw[4] = {s.x, s.y, s.z, s.w};
#pragma unroll
        for (int d = 0; d < 4; d++) {
            acc[2 * d]     = first ? b2f((unsigned short)(sw[d] & 0xFFFFu)) * dscale : 0.0f;
            acc[2 * d + 1] = first ? b2f((unsigned short)(sw[d] >> 16)) * dscale : 0.0f;
        }
    }
    int e = beg;
    for (; e + 32 <= end; e += 32) {
        unsigned int pk[4];
        uint4 g[4];
#pragma unroll
        for (int k = 0; k < 4; k++) pk[k] = csr4[e + 8 * k + slot];
#pragma unroll
        for (int k = 0; k < 4; k++) g[k] = srcU[((pk[k] >> 15) << 3) | dq];
#pragma unroll
        for (int k = 0; k < 4; k++) {
            float w = b2f((unsigned short)(pk[k] & 0x7FFFu));
            unsigned int gw[4] = {g[k].x, g[k].y, g[k].z, g[k].w};
#pragma unroll
            for (int d = 0; d < 4; d++) {
                acc[2 * d]     = fmaf(w, b2f((unsigned short)(gw[d] & 0xFFFFu)), acc[2 * d]);
                acc[2 * d + 1] = fmaf(w, b2f((unsigned short)(gw[d] >> 16)), acc[2 * d + 1]);
            }
        }
    }
    if (e + 16 <= end) {
        unsigned int pk[2];
        uint4 g[2];
#pragma unroll
        for (int k = 0; k < 2; k++) pk[k] = csr4[e + 8 * k + slot];
#pragma unroll
        for (int k = 0; k < 2; k++) g[k] = srcU[((pk[k] >> 15) << 3) | dq];
#pragma unroll
        for (int k = 0; k < 2; k++) {
            float w = b2f((unsigned short)(pk[k] & 0x7FFFu));
            unsigned int gw[4] = {g[k].x, g[k].y, g[k].z, g[k].w};
#pragma unroll
            for (int d = 0; d < 4; d++) {
                acc[2 * d]     = fmaf(w, b2f((unsigned short)(gw[d] & 0xFFFFu)), acc[2 * d]);
                acc[2 * d + 1] = fmaf(w, b2f((unsigned short)(gw[d] >> 16)), acc[2 * d + 1]);
            }
        }
        e += 16;
    }
    for (; e < end; e += 8) {
        int idx = e + slot;
        if (idx < end) {
            unsigned int pk = csr4[idx];
            uint4 g = srcU[((pk >> 15) << 3) | dq];
            float w = b2f((unsigned short)(pk & 0x7FFFu));
            unsigned int gw[4] = {g.x, g.y, g.z, g.w};
#pragma unroll
            for (int d = 0; d < 4; d++) {
                acc[2 * d]     = fmaf(w, b2f((unsigned short)(gw[d] & 0xFFFFu)), acc[2 * d]);
                acc[2 * d + 1] = fmaf(w, b2f((unsigned short)(gw[d] >> 16)), acc[2 * d + 1]);
            }
        }
    }
#pragma unroll
    for (int d = 0; d < 8; d++) {
        acc[d] += __shfl_xor(acc[d], 8);
        acc[d] += __shfl_xor(acc[d], 16);
        acc[d] += __shfl_xor(acc[d], 32);
    }
    if (slot == 0) {
        uint4 o;
        o.x = ((unsigned int)f2b(acc[1]) << 16) | (unsigned int)f2b(acc[0]);
        o.y = ((unsigned int)f2b(acc[3]) << 16) | (unsigned int)f2b(acc[2]);
        o.z = ((unsigned int)f2b(acc[5]) << 16) | (unsigned int)f2b(acc[4]);
        o.w = ((unsigned int)f2b(acc[7]) << 16) | (unsigned int)f2b(acc[6]);
        dstU[selfIdx] = o;
    }
}

// ---------------- BPR head ----------------
__global__ void __launch_bounds__(256) batch_kernel(
        const float* __restrict__ u0f, const float* __restrict__ i0f,
        const unsigned short* __restrict__ u1, const unsigned short* __restrict__ u2,
        const unsigned short* __restrict__ u3,
        const unsigned short* __restrict__ i1, const unsigned short* __restrict__ i2,
        const unsigned short* __restrict__ i3,
        const int* __restrict__ user, const int* __restrict__ ita, const int* __restrict__ itb,
        float* __restrict__ out, float* __restrict__ ls, float* __restrict__ l2a) {
    int wid = (blockIdx.x * 256 + threadIdx.x) >> 6;
    int lane = threadIdx.x & 63;
    if (wid >= BATCH) return;
    size_t uo = (size_t)user[wid] * FCT + lane;
    size_t ao = (size_t)ita[wid] * FCT + lane;
    size_t bo = (size_t)itb[wid] * FCT + lane;

    float pi, pj, l2;
    {
        float ue = u0f[uo], ie = i0f[ao], je = i0f[bo];
        pi = ue * ie; pj = ue * je; l2 = ue * ue + ie * ie + je * je;
    }
    const unsigned short* Ut[3] = {u1, u2, u3};
    const unsigned short* It[3] = {i1, i2, i3};
#pragma unroll
    for (int l = 0; l < 3; l++) {
        float ue = b2f(Ut[l][uo]), ie = b2f(It[l][ao]), je = b2f(It[l][bo]);
        pi += ue * ie;
        pj += ue * je;
        l2 += ue * ue + ie * ie + je * je;
    }
#pragma unroll
    for (int off = 32; off; off >>= 1) {
        pi += __shfl_xor(pi, off);
        pj += __shfl_xor(pj, off);
        l2 += __shfl_xor(l2, off);
    }
    if (lane == 0) {
        out[wid] = pi;
        out[BATCH + wid] = pj;
        float x = pi - pj;
        ls[wid] = fminf(x, 0.0f) - log1pf(expf(-fabsf(x)));
        l2a[wid] = 0.01f * l2;
    }
}

__global__ void final_kernel(const float* __restrict__ ls, const float* __restrict__ l2a,
                             float* __restrict__ out) {
    __shared__ float s1[256], s2[256];
    int t = threadIdx.x;
    float a = 0.f, b = 0.f;
    for (int i = t; i < BATCH; i += 256) {
        a += ls[i];
        b += l2a[i];
    }
    s1[t] = a;
    s2[t] = b;
    __syncthreads();
    for (int off = 128; off; off >>= 1) {
        if (t < off) {
            s1[t] += s1[t + off];
            s2[t] += s2[t + off];
        }
        __syncthreads();
    }
    if (t == 0) {
        float loss2 = -s1[0] / (float)BATCH;
        float l2m = s2[0] / (float)BATCH;
        out[2 * BATCH] = loss2 + l2m;
        out[2 * BATCH + 1] = loss2;
    }
}

// ---------------- launch ----------------
extern "C" void kernel_launch(void* const* d_in, const int* in_sizes, int n_in,
                              void* d_out, int out_size, void* d_ws, size_t ws_size,
                              hipStream_t stream) {
    const float* u0f = (const float*)d_in[0];
    const float* i0f = (const float*)d_in[1];
    const float* di  = (const float*)d_in[2];
    const float* dj  = (const float*)d_in[3];
    const float* vui = (const float*)d_in[4];
    const float* viu = (const float*)d_in[5];
    const int*   eu  = (const int*)d_in[6];
    const int*   ei  = (const int*)d_in[7];
    const int*   usr = (const int*)d_in[8];
    const int*   ita = (const int*)d_in[9];
    const int*   itb = (const int*)d_in[10];
    float* out = (float*)d_out;

    char* p = (char*)d_ws;
    auto alloc = [&](size_t bytes) -> char* {
        char* r = p;
        p += (bytes + 255) & ~(size_t)255;
        return r;
    };
    unsigned short* u0b = (unsigned short*)alloc((size_t)U_NUM * FCT * 2);
    unsigned short* u1b = (unsigned short*)alloc((size_t)U_NUM * FCT * 2);
    unsigned short* i0b = (unsigned short*)alloc((size_t)I_NUM * FCT * 2);
    unsigned short* i1b = (unsigned short*)alloc((size_t)I_NUM * FCT * 2);
    unsigned int* compact4   = (unsigned int*)alloc((size_t)TOTSLOTS * 4);    // 25.6 MB
    unsigned short* compactA = (unsigned short*)alloc((size_t)TOTSLOTS * 2);  // 12.8 MB
    unsigned int* staging4    = (unsigned int*)alloc((size_t)TOTSLOTS * 4);   // 25.6 MB
    unsigned char* staging_off = (unsigned char*)alloc((size_t)TOTSLOTS);     // 6.4 MB
    int* rowptr    = (int*)alloc((size_t)(NROWS + 1) * 4);
    int* cntmat256 = (int*)alloc((size_t)SUBS * NBUCK * 4);            // 2.4 MB
    int* localpfx  = (int*)alloc((size_t)NBUCK * SUBS * 4);            // 2.4 MB
    int* btot      = (int*)alloc((size_t)NBUCK * 4);
    int* bbase     = (int*)alloc((size_t)(NBUCK + 1) * 4);
    int* csum      = (int*)alloc((size_t)2048 * 4);
    int* cbase     = (int*)alloc((size_t)2049 * 4);
    float* ls      = (float*)alloc((size_t)BATCH * 4);
    float* l2a     = (float*)alloc((size_t)BATCH * 4);
    // overlays (disjoint lifetimes):
    //   csr4 <- compact4 ; i3b <- compactA ; u2b,u3b <- staging4 ; i2b <- staging_off
    unsigned int* csr4 = compact4;
    unsigned short* i3b = compactA;
    unsigned short* u2b = (unsigned short*)staging4;
    unsigned short* u3b = u2b + (size_t)U_NUM * FCT;
    unsigned short* i2b = (unsigned short*)staging_off;

    conv_kernel<<<(NROWS * FCT / 4 + 255) / 256, 256, 0, stream>>>(u0f, i0f, u0b, i0b);

    count256_kernel<<<SUBS, 1024, 0, stream>>>(eu, ei, cntmat256);
    bscan2_kernel<<<NBUCK, 256, 0, stream>>>(cntmat256, localpfx, btot);
    bscan_kernel<<<1, 256, 0, stream>>>(btot, bbase);
    csum_kernel<<<8, 256, 0, stream>>>(cntmat256, csum);
    cbase_kernel<<<1, 256, 0, stream>>>(csum, cbase);

    cscatA_kernel<<<SUBS, 1024, 0, stream>>>(eu, ei, vui, viu, cbase, compact4, compactA);
    scatterC_kernel<<<SUBS * 8, 256, 0, stream>>>(compact4, compactA, cntmat256, localpfx,
                                                  bbase, cbase, staging4, staging_off);
    rsort_kernel<<<NBUCK, 512, 0, stream>>>(bbase, staging4, staging_off, csr4, rowptr);

    int aggGrid = (NROWS * 64) / 256 + 1;
    agg_kernel<<<aggGrid, 256, 0, stream>>>(u0b, i0b, u1b, i1b, di, dj, rowptr, csr4);
    agg_kernel<<<aggGrid, 256, 0, stream>>>(u1b, i1b, u2b, i2b, di, dj, rowptr, csr4);
    agg_kernel<<<aggGrid, 256, 0, stream>>>(u2b, i2b, u3b, i3b, di, dj, rowptr, csr4);

    batch_kernel<<<(BATCH * 64) / 256, 256, 0, stream>>>(u0f, i0f, u1b, u2b, u3b,
                                                         i1b, i2b, i3b,
                                                         usr, ita, itb, out, ls, l2a);
    final_kernel<<<1, 256, 0, stream>>>(ls, l2a, out);
}